// Round 4
// baseline (1001.853 us; speedup 1.0000x reference)
//
#include <hip/hip_runtime.h>

#define NE 64
#define TAU 1e-4f

// ---------------- Kernel A: register-resident gate GEMM (f32) ---------------
// grid (N/64, ksplit), block 256 = 4 waves.
// Wave w owns experts [16w,16w+16); lane l owns token row0+l; acc[16] in VGPRs.
// A: per-lane sequential float4 loads of its own row (64B line reused across
// the 4 quads of each 16-k macro). B: wave-uniform pointer (readfirstlane) ->
// scalar/L1-broadcast loads. No LDS, no barriers -> no 128 B/cy LDS wall.
__global__ __launch_bounds__(256, 4) void gemm_reg(
    const float* __restrict__ X, const float* __restrict__ W,
    float* __restrict__ P0, float* __restrict__ P1, int H, int ksplit) {
  const int tid = threadIdx.x;
  const int lane = tid & 63;
  const int wave = tid >> 6;
  const int t = blockIdx.x * 64 + lane;
  const int kseg = H / ksplit;
  const int kbeg = blockIdx.y * kseg;
  float* __restrict__ P = blockIdx.y ? P1 : P0;

  const int we = __builtin_amdgcn_readfirstlane(wave << 4);
  const float4* __restrict__ xp =
      reinterpret_cast<const float4*>(X + (size_t)t * H + kbeg);
  const float4* __restrict__ bp =
      reinterpret_cast<const float4*>(W + (size_t)we * H + kbeg);
  const int H4 = H >> 2;

  float acc[16];
#pragma unroll
  for (int e = 0; e < 16; ++e) acc[e] = 0.f;

  const int QM = kseg >> 4;  // 16-k macros
  for (int m = 0; m < QM; ++m) {
    float4 a4[4];
#pragma unroll
    for (int q = 0; q < 4; ++q) a4[q] = xp[m * 4 + q];
#pragma unroll
    for (int q = 0; q < 4; ++q) {
#pragma unroll
      for (int e = 0; e < 16; ++e) {
        const float4 b4 = bp[(size_t)e * H4 + m * 4 + q];
        acc[e] = fmaf(a4[q].x, b4.x, acc[e]);
        acc[e] = fmaf(a4[q].y, b4.y, acc[e]);
        acc[e] = fmaf(a4[q].z, b4.z, acc[e]);
        acc[e] = fmaf(a4[q].w, b4.w, acc[e]);
      }
    }
  }
  float4* __restrict__ op = reinterpret_cast<float4*>(P + (size_t)t * NE + we);
#pragma unroll
  for (int j = 0; j < 4; ++j)
    op[j] = make_float4(acc[4 * j], acc[4 * j + 1], acc[4 * j + 2],
                        acc[4 * j + 3]);
}

// ------- Kernel B: merge k-halves + softmax + top-9 + deferral + hist -------
__global__ __launch_bounds__(256) void finish(
    const float* __restrict__ P1, int use1, const float* __restrict__ bias,
    float* __restrict__ S /* doubles as P0 */, float* __restrict__ wout,
    float* __restrict__ iout, int* __restrict__ cnt, int* __restrict__ hist,
    int* __restrict__ list, int cap, int K) {
  __shared__ int hist_s[NE];
  const int tid = threadIdx.x;
  if (tid < NE) hist_s[tid] = 0;
  __syncthreads();
  const int lane = tid & 63;
  const int wave = tid >> 6;
  const float bv = bias[lane];
  const int t0 = blockIdx.x * 64 + wave * 16;

  for (int tt = 0; tt < 16; ++tt) {
    const int t = t0 + tt;
    const size_t base = (size_t)t * NE;
    float s = S[base + lane] + bv;
    if (use1) s += P1[base + lane];

    float m = s;
#pragma unroll
    for (int off = 32; off >= 1; off >>= 1) m = fmaxf(m, __shfl_xor(m, off));
    const float e = expf(s - m);
    float sum = e;
#pragma unroll
    for (int off = 32; off >= 1; off >>= 1) sum += __shfl_xor(sum, off);
    const float p = e / sum;

    // top-9 on biased raw score, lowest-index tie-break (matches lax.top_k)
    float wsel = s;
    float rv = 0.f;
    int ri = 0;
    float prev = 0.f, mingap = 1e30f;
#pragma unroll
    for (int r = 0; r < 9; ++r) {
      float v = wsel;
      int ii = lane;
#pragma unroll
      for (int off = 32; off >= 1; off >>= 1) {
        const float ov = __shfl_xor(v, off);
        const int oi = __shfl_xor(ii, off);
        if (ov > v || (ov == v && oi < ii)) { v = ov; ii = oi; }
      }
      if (r > 0) mingap = fminf(mingap, prev - v);
      prev = v;
      const float pw = __shfl(p, ii);
      if (lane == r) { rv = pw; ri = ii; }
      if (lane == ii) wsel = -1e30f;
    }

    bool toC = false;
    if (mingap < TAU && cap > 0) {
      int pos = 0;
      if (lane == 0) pos = atomicAdd(cnt, 1);
      pos = __shfl(pos, 0);
      if (pos < cap) {
        if (lane == 0) list[pos] = t;
        toC = true;  // recompute kernel produces all outputs for this token
      }
    }
    if (!toC) {
      S[base + lane] = p;
      if (lane < K) {
        wout[(size_t)t * K + lane] = rv;
        iout[(size_t)t * K + lane] = (float)ri;
        atomicAdd(&hist_s[ri], 1);
      }
    }
  }
  __syncthreads();
  if (tid < NE) atomicAdd(&hist[tid], hist_s[tid]);
}

// -------- f64 finalize for one token (lanes 0..63 of wave 0) ---------------
__device__ __forceinline__ void finalize_token_f64(
    int t, int lane, double s, float* __restrict__ S, float* __restrict__ wout,
    float* __restrict__ iout, int* __restrict__ hist, int K) {
  double m = s;
#pragma unroll
  for (int off = 32; off >= 1; off >>= 1) m = fmax(m, __shfl_xor(m, off));
  const double ex = exp(s - m);
  double sum = ex;
#pragma unroll
  for (int off = 32; off >= 1; off >>= 1) sum += __shfl_xor(sum, off);
  const double p = ex / sum;
  S[(size_t)t * NE + lane] = (float)p;
  double wsel = s;
  double rv = 0.0;
  int ri = 0;
  for (int r = 0; r < K; ++r) {
    double v = wsel;
    int ii = lane;
#pragma unroll
    for (int off = 32; off >= 1; off >>= 1) {
      const double ov = __shfl_xor(v, off);
      const int oi = __shfl_xor(ii, off);
      if (ov > v || (ov == v && oi < ii)) { v = ov; ii = oi; }
    }
    const double pw = __shfl(p, ii);
    if (lane == r) { rv = pw; ri = ii; }
    if (lane == ii) wsel = -1e300;
  }
  if (lane < K) {
    wout[(size_t)t * K + lane] = (float)rv;
    iout[(size_t)t * K + lane] = (float)ri;
    atomicAdd(&hist[ri], 1);
  }
}

// ------- Kernel C: f64 recompute, 2 tokens/block sharing the W read ---------
__global__ __launch_bounds__(256) void recompute_f64(
    const float* __restrict__ X, const float* __restrict__ W,
    const float* __restrict__ bias, float* __restrict__ S,
    float* __restrict__ wout, float* __restrict__ iout,
    const int* __restrict__ cnt, const int* __restrict__ list,
    int* __restrict__ hist, int H, int K, int cap) {
  if (cap <= 0) return;
  __shared__ float4 xs[2][1024];  // 2 tokens x 4096 f32 = 32 KB
  __shared__ double red[256];
  const int tid = threadIdx.x;
  const int n = min(*cnt, cap);
  const int H4 = H >> 2;
  for (int bidx = blockIdx.x * 2; bidx < n; bidx += gridDim.x * 2) {
    const int t0 = list[bidx];
    const int t1 = (bidx + 1 < n) ? list[bidx + 1] : -1;
    __syncthreads();  // xs reuse from previous iteration
    const float4* x0g = reinterpret_cast<const float4*>(X + (size_t)t0 * H);
    const float4* x1g =
        reinterpret_cast<const float4*>(X + (size_t)(t1 >= 0 ? t1 : t0) * H);
    for (int i = tid; i < H4; i += 256) {
      xs[0][i] = x0g[i];
      xs[1][i] = x1g[i];
    }
    __syncthreads();
    const int e = tid & 63, sl = tid >> 6;
    const int seg = H4 >> 2;  // 256 float4 per slice
    const float4* wr = reinterpret_cast<const float4*>(W + (size_t)e * H) +
                       (size_t)sl * seg;
    const float4* x0 = &xs[0][sl * seg];
    const float4* x1 = &xs[1][sl * seg];
    double a0 = 0.0, a1 = 0.0;
    for (int k = 0; k < seg; ++k) {
      const float4 wv = wr[k];
      const float4 v0 = x0[k];
      const float4 v1 = x1[k];
      a0 = fma((double)v0.x, (double)wv.x, a0);
      a0 = fma((double)v0.y, (double)wv.y, a0);
      a0 = fma((double)v0.z, (double)wv.z, a0);
      a0 = fma((double)v0.w, (double)wv.w, a0);
      a1 = fma((double)v1.x, (double)wv.x, a1);
      a1 = fma((double)v1.y, (double)wv.y, a1);
      a1 = fma((double)v1.z, (double)wv.z, a1);
      a1 = fma((double)v1.w, (double)wv.w, a1);
    }
    red[tid] = a0;
    __syncthreads();
    if (tid < 64) {
      const double s = red[e] + red[64 + e] + red[128 + e] + red[192 + e] +
                       (double)bias[e];
      finalize_token_f64(t0, e, s, S, wout, iout, hist, K);
    }
    __syncthreads();
    red[tid] = a1;
    __syncthreads();
    if (tid < 64 && t1 >= 0) {
      const double s = red[e] + red[64 + e] + red[128 + e] + red[192 + e] +
                       (double)bias[e];
      finalize_token_f64(t1, e, s, S, wout, iout, hist, K);
    }
  }
}

// ------------- Kernel D: bias update from integer histogram -----------------
__global__ void bias_update(const int* __restrict__ hist,
                            const float* __restrict__ bias,
                            float* __restrict__ bout, float tpe) {
  const int e = threadIdx.x;
  const float d = (float)hist[e] - tpe;
  const float sg = (d > 0.f) ? 1.f : ((d < 0.f) ? -1.f : 0.f);
  bout[e] = bias[e] + 0.01f * sg;
}

extern "C" void kernel_launch(void* const* d_in, const int* in_sizes, int n_in,
                              void* d_out, int out_size, void* d_ws, size_t ws_size,
                              hipStream_t stream) {
  const float* x = (const float*)d_in[0];
  const float* w = (const float*)d_in[1];
  const float* bias = (const float*)d_in[2];
  const int E = in_sizes[2];                       // 64
  const int H = in_sizes[1] / E;                   // 4096
  const long long N = (long long)in_sizes[0] / H;  // 32768 tokens
  const int K = (int)(((long long)out_size - N * E - E) / (2 * N));  // 8

  float* S = (float*)d_out;            // [N][E] probs (holds P0 partial first)
  float* wout = S + (size_t)N * E;     // [N][K]
  float* iout = wout + (size_t)N * K;  // [N][K] indices as float
  float* bout = iout + (size_t)N * K;  // [E]

  // ws: [0,4) cnt | [256,512) hist | P1 @64KB ([N][64] f32, 8MB) | list after
  int* cnt = (int*)d_ws;
  int* hist = (int*)d_ws + 64;
  const size_t P1OFF = 65536;
  const size_t p1bytes = (size_t)N * NE * sizeof(float);
  float* P1 = (float*)((char*)d_ws + P1OFF);
  int ksplit = 1;
  int* list = (int*)d_ws + 256;
  size_t list_avail = (ws_size > 4096) ? (ws_size - 1024) : 0;
  if (ws_size >= P1OFF + p1bytes + 65536) {
    ksplit = 2;
    list = (int*)((char*)d_ws + P1OFF + p1bytes);
    list_avail = ws_size - P1OFF - p1bytes;
  }
  const int cap = (int)min((size_t)32768, list_avail / 4);
  if (ws_size >= 512) hipMemsetAsync(d_ws, 0, 512, stream);

  gemm_reg<<<dim3((int)(N / 64), ksplit), 256, 0, stream>>>(x, w, S, P1, H,
                                                            ksplit);
  finish<<<dim3((int)(N / 64)), 256, 0, stream>>>(
      P1, ksplit - 1, bias, S, wout, iout, cnt, hist, list, cap, K);
  recompute_f64<<<dim3(64), 256, 0, stream>>>(x, w, bias, S, wout, iout, cnt,
                                              list, hist, H, K, cap);
  bias_update<<<dim3(1), dim3(E), 0, stream>>>(hist, bias, bout,
                                               (float)((double)N * K / E));
}

// Round 5
// 631.103 us; speedup vs baseline: 1.5875x; 1.5875x over previous
//
#include <hip/hip_runtime.h>

#define NE 64
#define TAU 2.5e-4f
#define LSTR 68  // 68 mod 32 = 4 -> 2-way (free) LDS access in epilogue

typedef __bf16 bf16x8 __attribute__((ext_vector_type(8)));
typedef float f32x4 __attribute__((ext_vector_type(4)));

// split f32 -> bf16 hi + bf16 lo (hi RNE, lo = RNE(x - hi); x-hi exact in f32)
__device__ __forceinline__ void split8(const float4 a0, const float4 a1,
                                       bf16x8& hi, bf16x8& lo) {
  const float xs[8] = {a0.x, a0.y, a0.z, a0.w, a1.x, a1.y, a1.z, a1.w};
#pragma unroll
  for (int i = 0; i < 8; ++i) {
    const __bf16 h = (__bf16)xs[i];
    hi[i] = h;
    lo[i] = (__bf16)(xs[i] - (float)h);
  }
}

// ---------------- Kernel 0: W -> bf16 hi/lo (1 MB, runs once per launch) ----
__global__ __launch_bounds__(256) void wconvert(const float* __restrict__ W,
                                                __bf16* __restrict__ Whi,
                                                __bf16* __restrict__ Wlo,
                                                int n8) {
  const int i = blockIdx.x * 256 + threadIdx.x;
  if (i >= n8) return;
  const float4 a0 = reinterpret_cast<const float4*>(W)[2 * i];
  const float4 a1 = reinterpret_cast<const float4*>(W)[2 * i + 1];
  bf16x8 hi, lo;
  split8(a0, a1, hi, lo);
  *reinterpret_cast<bf16x8*>(Whi + 8 * i) = hi;
  *reinterpret_cast<bf16x8*>(Wlo + 8 * i) = lo;
}

// ------- Kernel 1: split-bf16 MFMA gate GEMM + fused softmax/top-9 ---------
// Block = 4 waves; wave w owns tokens [16w,16w+16); 4 B-fragments cover all
// 64 experts (shared across waves -> L1 broadcast; X read exactly once).
// A frag (16x16x32): lane holds X[row0+16w+(l&15)][32t + 8*(l>>4) + 0..7].
// B frag: lane holds W[16j+(l&15)][32t + 8*(l>>4) + 0..7] (row-major = B^T).
// C frag: col(expert-within-frag)=l&15, row(token-within-16)=4*(l>>4)+reg.
__global__ __launch_bounds__(256, 2) void gemm_fused(
    const float* __restrict__ X, const __bf16* __restrict__ Whi,
    const __bf16* __restrict__ Wlo, const float* __restrict__ bias,
    float* __restrict__ S, float* __restrict__ wout, float* __restrict__ iout,
    int* __restrict__ cnt, int* __restrict__ hist, int* __restrict__ list,
    int cap, int H, int K) {
  __shared__ float Ls[64 * LSTR];
  __shared__ int hist_s[NE];
  const int tid = threadIdx.x;
  const int lane = tid & 63;
  const int wave = tid >> 6;
  if (tid < NE) hist_s[tid] = 0;
  const int lr = lane & 15;   // row/col within fragment
  const int lk = lane >> 4;   // k sub-chunk (8 elements each)
  const int row0 = blockIdx.x * 64;

  const float* __restrict__ xp =
      X + (size_t)(row0 + 16 * wave + lr) * H + 8 * lk;
  const __bf16* __restrict__ bh[4];
  const __bf16* __restrict__ bl[4];
#pragma unroll
  for (int j = 0; j < 4; ++j) {
    bh[j] = Whi + (size_t)(16 * j + lr) * H + 8 * lk;
    bl[j] = Wlo + (size_t)(16 * j + lr) * H + 8 * lk;
  }

  f32x4 acc[4] = {};
  const int T = H / 32;
#pragma unroll 2
  for (int t = 0; t < T; ++t) {
    const float4 a0 = *reinterpret_cast<const float4*>(xp + 32 * t);
    const float4 a1 = *reinterpret_cast<const float4*>(xp + 32 * t + 4);
    bf16x8 Ahi, Alo;
    split8(a0, a1, Ahi, Alo);
#pragma unroll
    for (int j = 0; j < 4; ++j) {
      const bf16x8 Bh = *reinterpret_cast<const bf16x8*>(bh[j] + 32 * t);
      const bf16x8 Bl = *reinterpret_cast<const bf16x8*>(bl[j] + 32 * t);
      acc[j] = __builtin_amdgcn_mfma_f32_16x16x32_bf16(Alo, Bh, acc[j], 0, 0, 0);
      acc[j] = __builtin_amdgcn_mfma_f32_16x16x32_bf16(Ahi, Bl, acc[j], 0, 0, 0);
      acc[j] = __builtin_amdgcn_mfma_f32_16x16x32_bf16(Ahi, Bh, acc[j], 0, 0, 0);
    }
  }

  // ---- epilogue: transpose scores to token-major LDS ----
#pragma unroll
  for (int j = 0; j < 4; ++j)
#pragma unroll
    for (int r = 0; r < 4; ++r)
      Ls[(16 * wave + 4 * lk + r) * LSTR + 16 * j + lr] = acc[j][r];
  __syncthreads();

  const float bv = bias[lane];
  for (int tt = 0; tt < 16; ++tt) {
    const int tl = wave * 16 + tt;
    const int t = row0 + tl;
    const float s = Ls[tl * LSTR + lane] + bv;

    float m = s;
#pragma unroll
    for (int off = 32; off >= 1; off >>= 1) m = fmaxf(m, __shfl_xor(m, off));
    const float e = expf(s - m);
    float sum = e;
#pragma unroll
    for (int off = 32; off >= 1; off >>= 1) sum += __shfl_xor(sum, off);
    const float p = e / sum;

    // top-9 on biased raw score, lowest-index tie-break (matches lax.top_k)
    float wsel = s;
    float rv = 0.f;
    int ri = 0;
    float prev = 0.f, mingap = 1e30f;
#pragma unroll
    for (int r = 0; r < 9; ++r) {
      float v = wsel;
      int ii = lane;
#pragma unroll
      for (int off = 32; off >= 1; off >>= 1) {
        const float ov = __shfl_xor(v, off);
        const int oi = __shfl_xor(ii, off);
        if (ov > v || (ov == v && oi < ii)) { v = ov; ii = oi; }
      }
      if (r > 0) mingap = fminf(mingap, prev - v);
      prev = v;
      const float pw = __shfl(p, ii);
      if (lane == r) { rv = pw; ri = ii; }
      if (lane == ii) wsel = -1e30f;
    }

    bool toC = false;
    if (mingap < TAU && cap > 0) {
      int pos = 0;
      if (lane == 0) pos = atomicAdd(cnt, 1);
      pos = __shfl(pos, 0);
      if (pos < cap) {
        if (lane == 0) list[pos] = t;
        toC = true;  // recompute kernel produces all outputs for this token
      }
    }
    if (!toC) {
      S[(size_t)t * NE + lane] = p;
      if (lane < K) {
        wout[(size_t)t * K + lane] = rv;
        iout[(size_t)t * K + lane] = (float)ri;
        atomicAdd(&hist_s[ri], 1);
      }
    }
  }
  __syncthreads();
  if (tid < NE) atomicAdd(&hist[tid], hist_s[tid]);
}

// -------- f64 finalize for one token (lanes 0..63) ---------------
__device__ __forceinline__ void finalize_token_f64(
    int t, int lane, double s, float* __restrict__ S, float* __restrict__ wout,
    float* __restrict__ iout, int* __restrict__ hist, int K) {
  double m = s;
#pragma unroll
  for (int off = 32; off >= 1; off >>= 1) m = fmax(m, __shfl_xor(m, off));
  const double ex = exp(s - m);
  double sum = ex;
#pragma unroll
  for (int off = 32; off >= 1; off >>= 1) sum += __shfl_xor(sum, off);
  const double p = ex / sum;
  S[(size_t)t * NE + lane] = (float)p;
  double wsel = s;
  double rv = 0.0;
  int ri = 0;
  for (int r = 0; r < K; ++r) {
    double v = wsel;
    int ii = lane;
#pragma unroll
    for (int off = 32; off >= 1; off >>= 1) {
      const double ov = __shfl_xor(v, off);
      const int oi = __shfl_xor(ii, off);
      if (ov > v || (ov == v && oi < ii)) { v = ov; ii = oi; }
    }
    const double pw = __shfl(p, ii);
    if (lane == r) { rv = pw; ri = ii; }
    if (lane == ii) wsel = -1e300;
  }
  if (lane < K) {
    wout[(size_t)t * K + lane] = (float)rv;
    iout[(size_t)t * K + lane] = (float)ri;
    atomicAdd(&hist[ri], 1);
  }
}

// ------- Kernel 2: f64 recompute, 2 tokens/block sharing the W read ---------
__global__ __launch_bounds__(256) void recompute_f64(
    const float* __restrict__ X, const float* __restrict__ W,
    const float* __restrict__ bias, float* __restrict__ S,
    float* __restrict__ wout, float* __restrict__ iout,
    const int* __restrict__ cnt, const int* __restrict__ list,
    int* __restrict__ hist, int H, int K, int cap) {
  if (cap <= 0) return;
  __shared__ float4 xs[2][1024];
  __shared__ double red[256];
  const int tid = threadIdx.x;
  const int n = min(*cnt, cap);
  const int H4 = H >> 2;
  for (int bidx = blockIdx.x * 2; bidx < n; bidx += gridDim.x * 2) {
    const int t0 = list[bidx];
    const int t1 = (bidx + 1 < n) ? list[bidx + 1] : -1;
    __syncthreads();
    const float4* x0g = reinterpret_cast<const float4*>(X + (size_t)t0 * H);
    const float4* x1g =
        reinterpret_cast<const float4*>(X + (size_t)(t1 >= 0 ? t1 : t0) * H);
    for (int i = tid; i < H4; i += 256) {
      xs[0][i] = x0g[i];
      xs[1][i] = x1g[i];
    }
    __syncthreads();
    const int e = tid & 63, sl = tid >> 6;
    const int seg = H4 >> 2;
    const float4* wr =
        reinterpret_cast<const float4*>(W + (size_t)e * H) + (size_t)sl * seg;
    const float4* x0 = &xs[0][sl * seg];
    const float4* x1 = &xs[1][sl * seg];
    double a0 = 0.0, a1 = 0.0;
    for (int k = 0; k < seg; ++k) {
      const float4 wv = wr[k];
      const float4 v0 = x0[k];
      const float4 v1 = x1[k];
      a0 = fma((double)v0.x, (double)wv.x, a0);
      a0 = fma((double)v0.y, (double)wv.y, a0);
      a0 = fma((double)v0.z, (double)wv.z, a0);
      a0 = fma((double)v0.w, (double)wv.w, a0);
      a1 = fma((double)v1.x, (double)wv.x, a1);
      a1 = fma((double)v1.y, (double)wv.y, a1);
      a1 = fma((double)v1.z, (double)wv.z, a1);
      a1 = fma((double)v1.w, (double)wv.w, a1);
    }
    red[tid] = a0;
    __syncthreads();
    if (tid < 64) {
      const double s =
          red[e] + red[64 + e] + red[128 + e] + red[192 + e] + (double)bias[e];
      finalize_token_f64(t0, e, s, S, wout, iout, hist, K);
    }
    __syncthreads();
    red[tid] = a1;
    __syncthreads();
    if (tid < 64 && t1 >= 0) {
      const double s =
          red[e] + red[64 + e] + red[128 + e] + red[192 + e] + (double)bias[e];
      finalize_token_f64(t1, e, s, S, wout, iout, hist, K);
    }
  }
}

// ------------- Kernel 3: bias update from integer histogram -----------------
__global__ void bias_update(const int* __restrict__ hist,
                            const float* __restrict__ bias,
                            float* __restrict__ bout, float tpe) {
  const int e = threadIdx.x;
  const float d = (float)hist[e] - tpe;
  const float sg = (d > 0.f) ? 1.f : ((d < 0.f) ? -1.f : 0.f);
  bout[e] = bias[e] + 0.01f * sg;
}

extern "C" void kernel_launch(void* const* d_in, const int* in_sizes, int n_in,
                              void* d_out, int out_size, void* d_ws, size_t ws_size,
                              hipStream_t stream) {
  const float* x = (const float*)d_in[0];
  const float* w = (const float*)d_in[1];
  const float* bias = (const float*)d_in[2];
  const int E = in_sizes[2];                       // 64
  const int H = in_sizes[1] / E;                   // 4096
  const long long N = (long long)in_sizes[0] / H;  // 32768 tokens
  const int K = (int)(((long long)out_size - N * E - E) / (2 * N));  // 8

  float* S = (float*)d_out;            // [N][E] probs
  float* wout = S + (size_t)N * E;     // [N][K]
  float* iout = wout + (size_t)N * K;  // [N][K] indices as float
  float* bout = iout + (size_t)N * K;  // [E]

  // ws: [0,4) cnt | [256,512) hist | Whi @4KB (512KB) | Wlo | list after 1MB+4KB
  int* cnt = (int*)d_ws;
  int* hist = (int*)d_ws + 64;
  const size_t whalf = (size_t)E * H * sizeof(__bf16);  // 512 KB
  __bf16* Whi = (__bf16*)((char*)d_ws + 4096);
  __bf16* Wlo = (__bf16*)((char*)d_ws + 4096 + whalf);
  const size_t listoff = 4096 + 2 * whalf;
  int* list = (int*)((char*)d_ws + listoff);
  int cap = 0;
  if (ws_size > listoff + 65536)
    cap = (int)min((size_t)32768, (ws_size - listoff) / 4);
  if (ws_size >= 512) hipMemsetAsync(d_ws, 0, 512, stream);

  const int n8 = E * H / 8;
  wconvert<<<dim3((n8 + 255) / 256), 256, 0, stream>>>(w, Whi, Wlo, n8);
  gemm_fused<<<dim3((int)(N / 64)), 256, 0, stream>>>(
      x, Whi, Wlo, bias, S, wout, iout, cnt, hist, list, cap, H, K);
  recompute_f64<<<dim3(64), 256, 0, stream>>>(x, w, bias, S, wout, iout, cnt,
                                              list, hist, H, K, cap);
  bias_update<<<dim3(1), dim3(E), 0, stream>>>(hist, bias, bout,
                                               (float)((double)N * K / E));
}

// Round 6
// 535.933 us; speedup vs baseline: 1.8694x; 1.1776x over previous
//
#include <hip/hip_runtime.h>

#define NE 64
#define TAU 2.5e-4f
#define LSTR 68  // 68 mod 32 = 4 -> 2-way (free) LDS access in epilogue

typedef __bf16 bf16x8 __attribute__((ext_vector_type(8)));
typedef float f32x4 __attribute__((ext_vector_type(4)));

// split f32 -> bf16 hi + bf16 lo (hi RNE, lo = RNE(x - hi); x-hi exact in f32)
__device__ __forceinline__ void split8(const float4 a0, const float4 a1,
                                       bf16x8& hi, bf16x8& lo) {
  const float xs[8] = {a0.x, a0.y, a0.z, a0.w, a1.x, a1.y, a1.z, a1.w};
#pragma unroll
  for (int i = 0; i < 8; ++i) {
    const __bf16 h = (__bf16)xs[i];
    hi[i] = h;
    lo[i] = (__bf16)(xs[i] - (float)h);
  }
}

// ---------------- Kernel 0: W -> bf16 hi/lo (1 MB, once per launch) ---------
__global__ __launch_bounds__(256) void wconvert(const float* __restrict__ W,
                                                __bf16* __restrict__ Whi,
                                                __bf16* __restrict__ Wlo,
                                                int n8) {
  const int i = blockIdx.x * 256 + threadIdx.x;
  if (i >= n8) return;
  const float4 a0 = reinterpret_cast<const float4*>(W)[2 * i];
  const float4 a1 = reinterpret_cast<const float4*>(W)[2 * i + 1];
  bf16x8 hi, lo;
  split8(a0, a1, hi, lo);
  *reinterpret_cast<bf16x8*>(Whi + 8 * i) = hi;
  *reinterpret_cast<bf16x8*>(Wlo + 8 * i) = lo;
}

// ------- Kernel 1: split-bf16 MFMA gate GEMM + fused softmax/top-9 ---------
// Layout identical to round 5 (HW-validated). New: explicit 2-step software
// pipeline with named prefetch registers -> ~20 loads in flight per wave.
__global__ __launch_bounds__(256, 2) void gemm_fused(
    const float* __restrict__ X, const __bf16* __restrict__ Whi,
    const __bf16* __restrict__ Wlo, const float* __restrict__ bias,
    float* __restrict__ S, float* __restrict__ wout, float* __restrict__ iout,
    int* __restrict__ cnt, int* __restrict__ hist, int* __restrict__ list,
    int cap, int H, int K) {
  __shared__ float Ls[64 * LSTR];
  __shared__ int hist_s[NE];
  const int tid = threadIdx.x;
  const int lane = tid & 63;
  const int wave = tid >> 6;
  if (tid < NE) hist_s[tid] = 0;
  const int lr = lane & 15;  // row/col within fragment
  const int lk = lane >> 4;  // k sub-chunk (8 elements)
  const int row0 = blockIdx.x * 64;

  const float* __restrict__ xp =
      X + (size_t)(row0 + 16 * wave + lr) * H + 8 * lk;
  const __bf16* __restrict__ bh0 = Whi + (size_t)lr * H + 8 * lk;
  const __bf16* __restrict__ bl0 = Wlo + (size_t)lr * H + 8 * lk;

#define LDA0(t) *reinterpret_cast<const float4*>(xp + 32 * (t))
#define LDA1(t) *reinterpret_cast<const float4*>(xp + 32 * (t) + 4)
#define LDBH(j, t) \
  *reinterpret_cast<const bf16x8*>(bh0 + (size_t)(16 * (j)) * H + 32 * (t))
#define LDBL(j, t) \
  *reinterpret_cast<const bf16x8*>(bl0 + (size_t)(16 * (j)) * H + 32 * (t))

  f32x4 acc[4] = {};
  const int T = H / 32;  // 128 (even)

  // pipeline state: pair (t, t+1) resident; prefetch pair (t+2, t+3)
  float4 aA0 = LDA0(0), aA1 = LDA1(0), aB0 = LDA0(1), aB1 = LDA1(1);
  bf16x8 BhA[4], BlA[4], BhB[4], BlB[4];
#pragma unroll
  for (int j = 0; j < 4; ++j) {
    BhA[j] = LDBH(j, 0);
    BlA[j] = LDBL(j, 0);
    BhB[j] = LDBH(j, 1);
    BlB[j] = LDBL(j, 1);
  }

  for (int t = 0; t < T; t += 2) {
    const int tp0 = (t + 2 < T) ? t + 2 : t;  // clamped (last pair reloads)
    const int tp1 = (t + 3 < T) ? t + 3 : t + 1;
    // issue next-pair loads (no deps on compute below -> stay in flight)
    const float4 nA0 = LDA0(tp0), nA1 = LDA1(tp0);
    const float4 nB0 = LDA0(tp1), nB1 = LDA1(tp1);
    bf16x8 nBhA[4], nBlA[4], nBhB[4], nBlB[4];
#pragma unroll
    for (int j = 0; j < 4; ++j) {
      nBhA[j] = LDBH(j, tp0);
      nBlA[j] = LDBL(j, tp0);
      nBhB[j] = LDBH(j, tp1);
      nBlB[j] = LDBL(j, tp1);
    }
    // compute step t
    {
      bf16x8 Ahi, Alo;
      split8(aA0, aA1, Ahi, Alo);
#pragma unroll
      for (int j = 0; j < 4; ++j) {
        acc[j] =
            __builtin_amdgcn_mfma_f32_16x16x32_bf16(Alo, BhA[j], acc[j], 0, 0, 0);
        acc[j] =
            __builtin_amdgcn_mfma_f32_16x16x32_bf16(Ahi, BlA[j], acc[j], 0, 0, 0);
        acc[j] =
            __builtin_amdgcn_mfma_f32_16x16x32_bf16(Ahi, BhA[j], acc[j], 0, 0, 0);
      }
    }
    // compute step t+1
    {
      bf16x8 Ahi, Alo;
      split8(aB0, aB1, Ahi, Alo);
#pragma unroll
      for (int j = 0; j < 4; ++j) {
        acc[j] =
            __builtin_amdgcn_mfma_f32_16x16x32_bf16(Alo, BhB[j], acc[j], 0, 0, 0);
        acc[j] =
            __builtin_amdgcn_mfma_f32_16x16x32_bf16(Ahi, BlB[j], acc[j], 0, 0, 0);
        acc[j] =
            __builtin_amdgcn_mfma_f32_16x16x32_bf16(Ahi, BhB[j], acc[j], 0, 0, 0);
      }
    }
    // rotate
    aA0 = nA0;
    aA1 = nA1;
    aB0 = nB0;
    aB1 = nB1;
#pragma unroll
    for (int j = 0; j < 4; ++j) {
      BhA[j] = nBhA[j];
      BlA[j] = nBlA[j];
      BhB[j] = nBhB[j];
      BlB[j] = nBlB[j];
    }
  }
#undef LDA0
#undef LDA1
#undef LDBH
#undef LDBL

  // ---- epilogue: transpose scores to token-major LDS ----
#pragma unroll
  for (int j = 0; j < 4; ++j)
#pragma unroll
    for (int r = 0; r < 4; ++r)
      Ls[(16 * wave + 4 * lk + r) * LSTR + 16 * j + lr] = acc[j][r];
  __syncthreads();

  const float bv = bias[lane];
  for (int tt = 0; tt < 16; ++tt) {
    const int tl = wave * 16 + tt;
    const int t = row0 + tl;
    const float s = Ls[tl * LSTR + lane] + bv;

    float m = s;
#pragma unroll
    for (int off = 32; off >= 1; off >>= 1) m = fmaxf(m, __shfl_xor(m, off));
    const float e = expf(s - m);
    float sum = e;
#pragma unroll
    for (int off = 32; off >= 1; off >>= 1) sum += __shfl_xor(sum, off);
    const float p = e / sum;

    // top-9 on biased raw score, lowest-index tie-break (matches lax.top_k)
    float wsel = s;
    float rv = 0.f;
    int ri = 0;
    float prev = 0.f, mingap = 1e30f;
#pragma unroll
    for (int r = 0; r < 9; ++r) {
      float v = wsel;
      int ii = lane;
#pragma unroll
      for (int off = 32; off >= 1; off >>= 1) {
        const float ov = __shfl_xor(v, off);
        const int oi = __shfl_xor(ii, off);
        if (ov > v || (ov == v && oi < ii)) { v = ov; ii = oi; }
      }
      if (r > 0) mingap = fminf(mingap, prev - v);
      prev = v;
      const float pw = __shfl(p, ii);
      if (lane == r) { rv = pw; ri = ii; }
      if (lane == ii) wsel = -1e30f;
    }

    bool toC = false;
    if (mingap < TAU && cap > 0) {
      int pos = 0;
      if (lane == 0) pos = atomicAdd(cnt, 1);
      pos = __shfl(pos, 0);
      if (pos < cap) {
        if (lane == 0) list[pos] = t;
        toC = true;  // recompute kernel produces all outputs for this token
      }
    }
    if (!toC) {
      S[(size_t)t * NE + lane] = p;
      if (lane < K) {
        wout[(size_t)t * K + lane] = rv;
        iout[(size_t)t * K + lane] = (float)ri;
        atomicAdd(&hist_s[ri], 1);
      }
    }
  }
  __syncthreads();
  if (tid < NE) atomicAdd(&hist[tid], hist_s[tid]);
}

// -------- f64 finalize for one token (lanes 0..63) ---------------
__device__ __forceinline__ void finalize_token_f64(
    int t, int lane, double s, float* __restrict__ S, float* __restrict__ wout,
    float* __restrict__ iout, int* __restrict__ hist, int K) {
  double m = s;
#pragma unroll
  for (int off = 32; off >= 1; off >>= 1) m = fmax(m, __shfl_xor(m, off));
  const double ex = exp(s - m);
  double sum = ex;
#pragma unroll
  for (int off = 32; off >= 1; off >>= 1) sum += __shfl_xor(sum, off);
  const double p = ex / sum;
  S[(size_t)t * NE + lane] = (float)p;
  double wsel = s;
  double rv = 0.0;
  int ri = 0;
  for (int r = 0; r < K; ++r) {
    double v = wsel;
    int ii = lane;
#pragma unroll
    for (int off = 32; off >= 1; off >>= 1) {
      const double ov = __shfl_xor(v, off);
      const int oi = __shfl_xor(ii, off);
      if (ov > v || (ov == v && oi < ii)) { v = ov; ii = oi; }
    }
    const double pw = __shfl(p, ii);
    if (lane == r) { rv = pw; ri = ii; }
    if (lane == ii) wsel = -1e300;
  }
  if (lane < K) {
    wout[(size_t)t * K + lane] = (float)rv;
    iout[(size_t)t * K + lane] = (float)ri;
    atomicAdd(&hist[ri], 1);
  }
}

// ------- Kernel 2: f64 recompute, 1 token/block, grid 512 -------------------
__global__ __launch_bounds__(256) void recompute_f64(
    const float* __restrict__ X, const float* __restrict__ W,
    const float* __restrict__ bias, float* __restrict__ S,
    float* __restrict__ wout, float* __restrict__ iout,
    const int* __restrict__ cnt, const int* __restrict__ list,
    int* __restrict__ hist, int H, int K, int cap) {
  if (cap <= 0) return;
  __shared__ float4 xs[1024];  // one token row (16 KB)
  __shared__ double red[256];
  const int tid = threadIdx.x;
  const int n = min(*cnt, cap);
  const int H4 = H >> 2;
  for (int idx = blockIdx.x; idx < n; idx += gridDim.x) {
    const int t = list[idx];
    __syncthreads();  // xs reuse from previous iteration
    const float4* xg = reinterpret_cast<const float4*>(X + (size_t)t * H);
    for (int i = tid; i < H4; i += 256) xs[i] = xg[i];
    __syncthreads();
    const int e = tid & 63, sl = tid >> 6;
    const int seg = H4 >> 2;  // 256 float4 per slice
    const float4* wr =
        reinterpret_cast<const float4*>(W + (size_t)e * H) + (size_t)sl * seg;
    const float4* xr = &xs[sl * seg];
    double a0 = 0.0, a1 = 0.0;  // split accumulators (break f64 dep chain)
    for (int k = 0; k < seg; k += 2) {
      const float4 w0 = wr[k], w1 = wr[k + 1];
      const float4 v0 = xr[k], v1 = xr[k + 1];
      a0 = fma((double)v0.x, (double)w0.x, a0);
      a0 = fma((double)v0.y, (double)w0.y, a0);
      a0 = fma((double)v0.z, (double)w0.z, a0);
      a0 = fma((double)v0.w, (double)w0.w, a0);
      a1 = fma((double)v1.x, (double)w1.x, a1);
      a1 = fma((double)v1.y, (double)w1.y, a1);
      a1 = fma((double)v1.z, (double)w1.z, a1);
      a1 = fma((double)v1.w, (double)w1.w, a1);
    }
    red[tid] = a0 + a1;
    __syncthreads();
    if (tid < 64) {
      const double s =
          red[e] + red[64 + e] + red[128 + e] + red[192 + e] + (double)bias[e];
      finalize_token_f64(t, e, s, S, wout, iout, hist, K);
    }
  }
}

// ------------- Kernel 3: bias update from integer histogram -----------------
__global__ void bias_update(const int* __restrict__ hist,
                            const float* __restrict__ bias,
                            float* __restrict__ bout, float tpe) {
  const int e = threadIdx.x;
  const float d = (float)hist[e] - tpe;
  const float sg = (d > 0.f) ? 1.f : ((d < 0.f) ? -1.f : 0.f);
  bout[e] = bias[e] + 0.01f * sg;
}

extern "C" void kernel_launch(void* const* d_in, const int* in_sizes, int n_in,
                              void* d_out, int out_size, void* d_ws, size_t ws_size,
                              hipStream_t stream) {
  const float* x = (const float*)d_in[0];
  const float* w = (const float*)d_in[1];
  const float* bias = (const float*)d_in[2];
  const int E = in_sizes[2];                       // 64
  const int H = in_sizes[1] / E;                   // 4096
  const long long N = (long long)in_sizes[0] / H;  // 32768 tokens
  const int K = (int)(((long long)out_size - N * E - E) / (2 * N));  // 8

  float* S = (float*)d_out;            // [N][E] probs
  float* wout = S + (size_t)N * E;     // [N][K]
  float* iout = wout + (size_t)N * K;  // [N][K] indices as float
  float* bout = iout + (size_t)N * K;  // [E]

  // ws: [0,4) cnt | [256,512) hist | Whi @4KB (512KB) | Wlo | list after
  int* cnt = (int*)d_ws;
  int* hist = (int*)d_ws + 64;
  const size_t whalf = (size_t)E * H * sizeof(__bf16);  // 512 KB
  __bf16* Whi = (__bf16*)((char*)d_ws + 4096);
  __bf16* Wlo = (__bf16*)((char*)d_ws + 4096 + whalf);
  const size_t listoff = 4096 + 2 * whalf;
  int* list = (int*)((char*)d_ws + listoff);
  int cap = 0;
  if (ws_size > listoff + 65536)
    cap = (int)min((size_t)32768, (ws_size - listoff) / 4);
  if (ws_size >= 512) hipMemsetAsync(d_ws, 0, 512, stream);

  const int n8 = E * H / 8;
  wconvert<<<dim3((n8 + 255) / 256), 256, 0, stream>>>(w, Whi, Wlo, n8);
  gemm_fused<<<dim3((int)(N / 64)), 256, 0, stream>>>(
      x, Whi, Wlo, bias, S, wout, iout, cnt, hist, list, cap, H, K);
  recompute_f64<<<dim3(512), 256, 0, stream>>>(x, w, bias, S, wout, iout, cnt,
                                               list, hist, H, K, cap);
  bias_update<<<dim3(1), dim3(E), 0, stream>>>(hist, bias, bout,
                                               (float)((double)N * K / E));
}

// Round 7
// 375.844 us; speedup vs baseline: 2.6656x; 1.4259x over previous
//
#include <hip/hip_runtime.h>

#define NE 64
#define TAU 2.5e-4f
#define LSTR 68  // 68 mod 32 = 4 -> 2-way (free) LDS access in epilogue

typedef __bf16 bf16x8 __attribute__((ext_vector_type(8)));
typedef float f32x4 __attribute__((ext_vector_type(4)));

// split f32 -> bf16 hi + bf16 lo (hi RNE, lo = RNE(x - hi); x-hi exact in f32)
__device__ __forceinline__ void split8(const float4 a0, const float4 a1,
                                       bf16x8& hi, bf16x8& lo) {
  const float xs[8] = {a0.x, a0.y, a0.z, a0.w, a1.x, a1.y, a1.z, a1.w};
#pragma unroll
  for (int i = 0; i < 8; ++i) {
    const __bf16 h = (__bf16)xs[i];
    hi[i] = h;
    lo[i] = (__bf16)(xs[i] - (float)h);
  }
}

// async global->LDS, 16B/lane; LDS dest = wave-uniform base + lane*16
__device__ __forceinline__ void gld16(const void* g, void* l) {
  __builtin_amdgcn_global_load_lds(
      (const __attribute__((address_space(1))) void*)g,
      (__attribute__((address_space(3))) void*)l, 16, 0, 0);
}

// ---- Kernel 0: W -> bf16 hi/lo in FRAGMENT-MAJOR layout (1 MB, once) ------
// Layout: elem(t, j, lk, lr, kr) = t*2048 + j*512 + (lk*16+lr)*8 + kr
// where W-row e = 16j+lr, k = 32t + 8lk + kr. Makes B staging linear-global
// -> linear-LDS and B ds_read_b128 lane-contiguous (conflict-free).
__global__ __launch_bounds__(256) void wconvert(const float* __restrict__ W,
                                                __bf16* __restrict__ Whi,
                                                __bf16* __restrict__ Wlo,
                                                int n8, int H) {
  const int i = blockIdx.x * 256 + threadIdx.x;
  if (i >= n8) return;
  const int hc = H >> 3;
  const int e = i / hc;
  const int k0 = (i - e * hc) * 8;
  const float4 a0 = *reinterpret_cast<const float4*>(W + (size_t)e * H + k0);
  const float4 a1 =
      *reinterpret_cast<const float4*>(W + (size_t)e * H + k0 + 4);
  bf16x8 hi, lo;
  split8(a0, a1, hi, lo);
  const int t = k0 >> 5, lk = (k0 >> 3) & 3, j = e >> 4, lr = e & 15;
  const size_t off = (size_t)t * 2048 + j * 512 + (lk * 16 + lr) * 8;
  *reinterpret_cast<bf16x8*>(Whi + off) = hi;
  *reinterpret_cast<bf16x8*>(Wlo + off) = lo;
}

// ------- Kernel 1: split-bf16 MFMA GEMM, gload_lds double-buffered ---------
// Block = 4 waves, 64 tokens. Per k-step (32 k): stage A (64x32 f32, 8 KB,
// two 16B planes per wave -> lane-linear reads) + Bh/Bl (fragment-major,
// 4 KB each) via 4 gload_lds per wave; counted vmcnt(4); raw s_barrier.
// MFMA layout identical to round 5 (HW-validated).
__global__ __launch_bounds__(256, 2) void gemm_fused(
    const float* __restrict__ X, const __bf16* __restrict__ Whi,
    const __bf16* __restrict__ Wlo, const float* __restrict__ bias,
    float* __restrict__ S, float* __restrict__ wout, float* __restrict__ iout,
    int* __restrict__ cnt, int* __restrict__ hist, int* __restrict__ list,
    int cap, int H, int K) {
  __shared__ alignas(16) char smem[32768];
  __shared__ int hist_s[NE];
  const int tid = threadIdx.x;
  const int lane = tid & 63;
  const int wave = tid >> 6;
  if (tid < NE) hist_s[tid] = 0;
  const int lr = lane & 15;  // fragment row/col
  const int lk = lane >> 4;  // k sub-chunk
  const int row0 = blockIdx.x * 64;

  // staging sources (advance per t)
  const float* srcA0 =
      X + (size_t)(row0 + 16 * wave + lr) * H + 8 * lk;        // plane 0
  const float* srcA1 = srcA0 + 4;                              // plane 1
  const __bf16* srcBh = Whi + wave * 512 + lane * 8;
  const __bf16* srcBl = Wlo + wave * 512 + lane * 8;

#define AB(buf) ((float*)smem + (buf)*2048)
#define BHB(buf) ((__bf16*)(smem + 16384) + (buf)*2048)
#define BLB(buf) ((__bf16*)(smem + 24576) + (buf)*2048)
#define ISSUE(t, buf)                                      \
  do {                                                     \
    gld16(srcA0 + 32 * (t), AB(buf) + wave * 512);         \
    gld16(srcA1 + 32 * (t), AB(buf) + wave * 512 + 256);   \
    gld16(srcBh + 2048 * (size_t)(t), BHB(buf) + wave * 512); \
    gld16(srcBl + 2048 * (size_t)(t), BLB(buf) + wave * 512); \
  } while (0)

  f32x4 acc[4] = {};
  const int T = H / 32;  // 128

  ISSUE(0, 0);
  for (int t = 0; t < T; ++t) {
    const int buf = t & 1;
    if (t + 1 < T) {
      ISSUE(t + 1, buf ^ 1);
      asm volatile("s_waitcnt vmcnt(4)" ::: "memory");  // tile t landed
    } else {
      asm volatile("s_waitcnt vmcnt(0)" ::: "memory");
    }
    __builtin_amdgcn_s_barrier();
    asm volatile("" ::: "memory");

    const float* Ab = AB(buf) + wave * 512;
    const float4 f0 = *reinterpret_cast<const float4*>(Ab + lane * 4);
    const float4 f1 = *reinterpret_cast<const float4*>(Ab + 256 + lane * 4);
    bf16x8 BH[4], BL[4];
    const __bf16* Bhb = BHB(buf);
    const __bf16* Blb = BLB(buf);
#pragma unroll
    for (int j = 0; j < 4; ++j) {
      BH[j] = *reinterpret_cast<const bf16x8*>(Bhb + j * 512 + lane * 8);
      BL[j] = *reinterpret_cast<const bf16x8*>(Blb + j * 512 + lane * 8);
    }
    bf16x8 Ahi, Alo;
    split8(f0, f1, Ahi, Alo);
#pragma unroll
    for (int j = 0; j < 4; ++j) {
      acc[j] = __builtin_amdgcn_mfma_f32_16x16x32_bf16(Alo, BH[j], acc[j], 0, 0, 0);
      acc[j] = __builtin_amdgcn_mfma_f32_16x16x32_bf16(Ahi, BL[j], acc[j], 0, 0, 0);
      acc[j] = __builtin_amdgcn_mfma_f32_16x16x32_bf16(Ahi, BH[j], acc[j], 0, 0, 0);
    }
    asm volatile("" ::: "memory");
    __builtin_amdgcn_s_barrier();
    asm volatile("" ::: "memory");
  }
#undef ISSUE
#undef AB
#undef BHB
#undef BLB

  // ---- epilogue: transpose scores to token-major LDS (aliases smem) ----
  float* Ls = (float*)smem;  // 64*68*4 = 17408 B <= 32768
#pragma unroll
  for (int j = 0; j < 4; ++j)
#pragma unroll
    for (int r = 0; r < 4; ++r)
      Ls[(16 * wave + 4 * lk + r) * LSTR + 16 * j + lr] = acc[j][r];
  __syncthreads();

  const float bv = bias[lane];
  for (int tt = 0; tt < 16; ++tt) {
    const int tl = wave * 16 + tt;
    const int t = row0 + tl;
    const float s = Ls[tl * LSTR + lane] + bv;

    float m = s;
#pragma unroll
    for (int off = 32; off >= 1; off >>= 1) m = fmaxf(m, __shfl_xor(m, off));
    const float e = expf(s - m);
    float sum = e;
#pragma unroll
    for (int off = 32; off >= 1; off >>= 1) sum += __shfl_xor(sum, off);
    const float p = e / sum;

    // top-9 on biased raw score, lowest-index tie-break (matches lax.top_k)
    float wsel = s;
    float rv = 0.f;
    int ri = 0;
    float prev = 0.f, mingap = 1e30f;
#pragma unroll
    for (int r = 0; r < 9; ++r) {
      float v = wsel;
      int ii = lane;
#pragma unroll
      for (int off = 32; off >= 1; off >>= 1) {
        const float ov = __shfl_xor(v, off);
        const int oi = __shfl_xor(ii, off);
        if (ov > v || (ov == v && oi < ii)) { v = ov; ii = oi; }
      }
      if (r > 0) mingap = fminf(mingap, prev - v);
      prev = v;
      const float pw = __shfl(p, ii);
      if (lane == r) { rv = pw; ri = ii; }
      if (lane == ii) wsel = -1e30f;
    }

    bool toC = false;
    if (mingap < TAU && cap > 0) {
      int pos = 0;
      if (lane == 0) pos = atomicAdd(cnt, 1);
      pos = __shfl(pos, 0);
      if (pos < cap) {
        if (lane == 0) list[pos] = t;
        toC = true;  // recompute kernel produces all outputs for this token
      }
    }
    if (!toC) {
      S[(size_t)t * NE + lane] = p;
      if (lane < K) {
        wout[(size_t)t * K + lane] = rv;
        iout[(size_t)t * K + lane] = (float)ri;
        atomicAdd(&hist_s[ri], 1);
      }
    }
  }
  __syncthreads();
  if (tid < NE) atomicAdd(&hist[tid], hist_s[tid]);
}

// -------- f64 finalize for one token (lanes 0..63) ---------------
__device__ __forceinline__ void finalize_token_f64(
    int t, int lane, double s, float* __restrict__ S, float* __restrict__ wout,
    float* __restrict__ iout, int* __restrict__ hist, int K) {
  double m = s;
#pragma unroll
  for (int off = 32; off >= 1; off >>= 1) m = fmax(m, __shfl_xor(m, off));
  const double ex = exp(s - m);
  double sum = ex;
#pragma unroll
  for (int off = 32; off >= 1; off >>= 1) sum += __shfl_xor(sum, off);
  const double p = ex / sum;
  S[(size_t)t * NE + lane] = (float)p;
  double wsel = s;
  double rv = 0.0;
  int ri = 0;
  for (int r = 0; r < K; ++r) {
    double v = wsel;
    int ii = lane;
#pragma unroll
    for (int off = 32; off >= 1; off >>= 1) {
      const double ov = __shfl_xor(v, off);
      const int oi = __shfl_xor(ii, off);
      if (ov > v || (ov == v && oi < ii)) { v = ov; ii = oi; }
    }
    const double pw = __shfl(p, ii);
    if (lane == r) { rv = pw; ri = ii; }
    if (lane == ii) wsel = -1e300;
  }
  if (lane < K) {
    wout[(size_t)t * K + lane] = (float)rv;
    iout[(size_t)t * K + lane] = (float)ri;
    atomicAdd(&hist[ri], 1);
  }
}

// ------- Kernel 2: f64 recompute, 1 token/block, grid 512 -------------------
__global__ __launch_bounds__(256) void recompute_f64(
    const float* __restrict__ X, const float* __restrict__ W,
    const float* __restrict__ bias, float* __restrict__ S,
    float* __restrict__ wout, float* __restrict__ iout,
    const int* __restrict__ cnt, const int* __restrict__ list,
    int* __restrict__ hist, int H, int K, int cap) {
  if (cap <= 0) return;
  __shared__ float4 xs[1024];  // one token row (16 KB)
  __shared__ double red[256];
  const int tid = threadIdx.x;
  const int n = min(*cnt, cap);
  const int H4 = H >> 2;
  for (int idx = blockIdx.x; idx < n; idx += gridDim.x) {
    const int t = list[idx];
    __syncthreads();  // xs reuse from previous iteration
    const float4* xg = reinterpret_cast<const float4*>(X + (size_t)t * H);
    for (int i = tid; i < H4; i += 256) xs[i] = xg[i];
    __syncthreads();
    const int e = tid & 63, sl = tid >> 6;
    const int seg = H4 >> 2;  // 256 float4 per slice
    const float4* wr =
        reinterpret_cast<const float4*>(W + (size_t)e * H) + (size_t)sl * seg;
    const float4* xr = &xs[sl * seg];
    double a0 = 0.0, a1 = 0.0;  // split accumulators (break f64 dep chain)
    for (int k = 0; k < seg; k += 2) {
      const float4 w0 = wr[k], w1 = wr[k + 1];
      const float4 v0 = xr[k], v1 = xr[k + 1];
      a0 = fma((double)v0.x, (double)w0.x, a0);
      a0 = fma((double)v0.y, (double)w0.y, a0);
      a0 = fma((double)v0.z, (double)w0.z, a0);
      a0 = fma((double)v0.w, (double)w0.w, a0);
      a1 = fma((double)v1.x, (double)w1.x, a1);
      a1 = fma((double)v1.y, (double)w1.y, a1);
      a1 = fma((double)v1.z, (double)w1.z, a1);
      a1 = fma((double)v1.w, (double)w1.w, a1);
    }
    red[tid] = a0 + a1;
    __syncthreads();
    if (tid < 64) {
      const double s =
          red[e] + red[64 + e] + red[128 + e] + red[192 + e] + (double)bias[e];
      finalize_token_f64(t, e, s, S, wout, iout, hist, K);
    }
  }
}

// ------------- Kernel 3: bias update from integer histogram -----------------
__global__ void bias_update(const int* __restrict__ hist,
                            const float* __restrict__ bias,
                            float* __restrict__ bout, float tpe) {
  const int e = threadIdx.x;
  const float d = (float)hist[e] - tpe;
  const float sg = (d > 0.f) ? 1.f : ((d < 0.f) ? -1.f : 0.f);
  bout[e] = bias[e] + 0.01f * sg;
}

extern "C" void kernel_launch(void* const* d_in, const int* in_sizes, int n_in,
                              void* d_out, int out_size, void* d_ws, size_t ws_size,
                              hipStream_t stream) {
  const float* x = (const float*)d_in[0];
  const float* w = (const float*)d_in[1];
  const float* bias = (const float*)d_in[2];
  const int E = in_sizes[2];                       // 64
  const int H = in_sizes[1] / E;                   // 4096
  const long long N = (long long)in_sizes[0] / H;  // 32768 tokens
  const int K = (int)(((long long)out_size - N * E - E) / (2 * N));  // 8

  float* S = (float*)d_out;            // [N][E] probs
  float* wout = S + (size_t)N * E;     // [N][K]
  float* iout = wout + (size_t)N * K;  // [N][K] indices as float
  float* bout = iout + (size_t)N * K;  // [E]

  // ws: [0,4) cnt | [256,512) hist | Whi_f @4KB (512KB) | Wlo_f | list after
  int* cnt = (int*)d_ws;
  int* hist = (int*)d_ws + 64;
  const size_t whalf = (size_t)E * H * sizeof(__bf16);  // 512 KB
  __bf16* Whi = (__bf16*)((char*)d_ws + 4096);
  __bf16* Wlo = (__bf16*)((char*)d_ws + 4096 + whalf);
  const size_t listoff = 4096 + 2 * whalf;
  int* list = (int*)((char*)d_ws + listoff);
  int cap = 0;
  if (ws_size > listoff + 65536)
    cap = (int)min((size_t)32768, (ws_size - listoff) / 4);
  if (ws_size >= 512) hipMemsetAsync(d_ws, 0, 512, stream);

  const int n8 = E * H / 8;
  wconvert<<<dim3((n8 + 255) / 256), 256, 0, stream>>>(w, Whi, Wlo, n8, H);
  gemm_fused<<<dim3((int)(N / 64)), 256, 0, stream>>>(
      x, Whi, Wlo, bias, S, wout, iout, cnt, hist, list, cap, H, K);
  recompute_f64<<<dim3(512), 256, 0, stream>>>(x, w, bias, S, wout, iout, cnt,
                                               list, hist, H, K, cap);
  bias_update<<<dim3(1), dim3(E), 0, stream>>>(hist, bias, bout,
                                               (float)((double)N * K / E));
}

// Round 8
// 366.733 us; speedup vs baseline: 2.7318x; 1.0248x over previous
//
#include <hip/hip_runtime.h>

#define NE 64
#define TAU 2.5e-4f
#define LSTR 68  // 68 mod 32 = 4 -> 2-way (free) LDS access in epilogue

typedef __bf16 bf16x8 __attribute__((ext_vector_type(8)));
typedef float f32x4 __attribute__((ext_vector_type(4)));

// split f32 -> bf16 hi + bf16 lo (hi RNE, lo = RNE(x - hi); x-hi exact in f32)
__device__ __forceinline__ void split8(const float4 a0, const float4 a1,
                                       bf16x8& hi, bf16x8& lo) {
  const float xs[8] = {a0.x, a0.y, a0.z, a0.w, a1.x, a1.y, a1.z, a1.w};
#pragma unroll
  for (int i = 0; i < 8; ++i) {
    const __bf16 h = (__bf16)xs[i];
    hi[i] = h;
    lo[i] = (__bf16)(xs[i] - (float)h);
  }
}

// async global->LDS, 16B/lane; LDS dest = wave-uniform base + lane*16
__device__ __forceinline__ void gld16(const void* g, void* l) {
  __builtin_amdgcn_global_load_lds(
      (const __attribute__((address_space(1))) void*)g,
      (__attribute__((address_space(3))) void*)l, 16, 0, 0);
}

// A-tile slot swizzle: row r (0..15), logical 16B-chunk c (0..7) stored at
// phys slot c ^ perm(r). perm spreads the 8 chunk-slots across 8 bank-groups.
__device__ __forceinline__ int permA(int r) {
  return ((r & 3) << 1) | ((r >> 2) & 1);
}

// ---- Kernel Z: zero cnt+hist (replaces hipMemsetAsync/fillBuffer) ----------
__global__ void zero512(int* __restrict__ p) { p[threadIdx.x] = 0; }

// ---- Kernel 0: W -> bf16 hi/lo in FRAGMENT-MAJOR layout (1 MB, once) ------
// elem(t, j, lk, lr, kr) = t*2048 + j*512 + (lk*16+lr)*8 + kr
// where W-row e = 16j+lr, k = 32t + 8lk + kr. B staging is linear-global ->
// linear-LDS; B ds_read_b128 lane-contiguous (conflict-free).
__global__ __launch_bounds__(256) void wconvert(const float* __restrict__ W,
                                                __bf16* __restrict__ Whi,
                                                __bf16* __restrict__ Wlo,
                                                int n8, int H) {
  const int i = blockIdx.x * 256 + threadIdx.x;
  if (i >= n8) return;
  const int hc = H >> 3;
  const int e = i / hc;
  const int k0 = (i - e * hc) * 8;
  const float4 a0 = *reinterpret_cast<const float4*>(W + (size_t)e * H + k0);
  const float4 a1 =
      *reinterpret_cast<const float4*>(W + (size_t)e * H + k0 + 4);
  bf16x8 hi, lo;
  split8(a0, a1, hi, lo);
  const int t = k0 >> 5, lk = (k0 >> 3) & 3, j = e >> 4, lr = e & 15;
  const size_t off = (size_t)t * 2048 + j * 512 + (lk * 16 + lr) * 8;
  *reinterpret_cast<bf16x8*>(Whi + off) = hi;
  *reinterpret_cast<bf16x8*>(Wlo + off) = lo;
}

// ------- Kernel 1: split-bf16 MFMA GEMM, 3-deep gload_lds pipeline ---------
// Block = 4 waves, 64 tokens, 3 LDS buffers (48 KB -> 3 blocks/CU).
// Per 32-k step, per wave: 2 gld16 A (row-major [16][32] swizzled, fully
// coalesced 128 B/row) + 2 gld16 B (fragment-major, linear). vmcnt(8) keeps
// 2 future tiles in flight. Two drain-free s_barriers per step.
__global__ __launch_bounds__(256, 3) void gemm_fused(
    const float* __restrict__ X, const __bf16* __restrict__ Whi,
    const __bf16* __restrict__ Wlo, const float* __restrict__ bias,
    float* __restrict__ S, float* __restrict__ wout, float* __restrict__ iout,
    int* __restrict__ cnt, int* __restrict__ hist, int* __restrict__ list,
    int cap, int H, int K) {
  __shared__ alignas(16) char smem[49152];
  __shared__ int hist_s[NE];
  const int tid = threadIdx.x;
  const int lane = tid & 63;
  const int wave = tid >> 6;
  if (tid < NE) hist_s[tid] = 0;
  const int lr = lane & 15;  // fragment row/col
  const int lk = lane >> 4;  // k sub-chunk
  const int row0 = blockIdx.x * 64;

  // A staging sources: instr p (0/1), lane l -> row rloc = p*8 + (l>>3),
  // phys slot s = l&7, logical chunk c = s ^ permA(rloc), col = 4c.
  const int rloc0 = lane >> 3;        // p=0 rows 0..7
  const int rloc1 = 8 + (lane >> 3);  // p=1 rows 8..15
  const int sA = lane & 7;
  const float* srcA0 = X + (size_t)(row0 + 16 * wave + rloc0) * H +
                       4 * (sA ^ permA(rloc0));
  const float* srcA1 = X + (size_t)(row0 + 16 * wave + rloc1) * H +
                       4 * (sA ^ permA(rloc1));
  const __bf16* srcBh = Whi + wave * 512 + lane * 8;
  const __bf16* srcBl = Wlo + wave * 512 + lane * 8;

#define AB(buf) ((float*)smem + (size_t)(buf)*2048)
#define BHB(buf) ((__bf16*)(smem + 24576) + (size_t)(buf)*2048)
#define BLB(buf) ((__bf16*)(smem + 36864) + (size_t)(buf)*2048)
#define ISSUE(t, buf)                                            \
  do {                                                           \
    gld16(srcA0 + 32 * (size_t)(t), AB(buf) + wave * 512);       \
    gld16(srcA1 + 32 * (size_t)(t), AB(buf) + wave * 512 + 256); \
    gld16(srcBh + 2048 * (size_t)(t), BHB(buf) + wave * 512);    \
    gld16(srcBl + 2048 * (size_t)(t), BLB(buf) + wave * 512);    \
  } while (0)

  f32x4 acc[4] = {};
  const int T = H / 32;  // 128
  const int s0 = (2 * lk) ^ permA(lr);  // A read slots (s1 = s0^1)

  ISSUE(0, 0);
  ISSUE(1, 1);
  for (int t = 0; t < T; ++t) {
    const int buf = t % 3;
    if (t + 2 < T) {
      ISSUE(t + 2, (t + 2) % 3);
      asm volatile("s_waitcnt vmcnt(8)" ::: "memory");  // tile t landed
    } else if (t + 1 < T) {
      asm volatile("s_waitcnt vmcnt(4)" ::: "memory");
    } else {
      asm volatile("s_waitcnt vmcnt(0)" ::: "memory");
    }
    __builtin_amdgcn_s_barrier();
    asm volatile("" ::: "memory");

    const float* Ab = AB(buf) + wave * 512 + lr * 32;
    const float4 f0 = *reinterpret_cast<const float4*>(Ab + s0 * 4);
    const float4 f1 = *reinterpret_cast<const float4*>(Ab + (s0 ^ 1) * 4);
    bf16x8 BH[4], BL[4];
    const __bf16* Bhb = BHB(buf);
    const __bf16* Blb = BLB(buf);
#pragma unroll
    for (int j = 0; j < 4; ++j) {
      BH[j] = *reinterpret_cast<const bf16x8*>(Bhb + j * 512 + lane * 8);
      BL[j] = *reinterpret_cast<const bf16x8*>(Blb + j * 512 + lane * 8);
    }
    bf16x8 Ahi, Alo;
    split8(f0, f1, Ahi, Alo);
#pragma unroll
    for (int j = 0; j < 4; ++j) {
      acc[j] = __builtin_amdgcn_mfma_f32_16x16x32_bf16(Alo, BH[j], acc[j], 0, 0, 0);
      acc[j] = __builtin_amdgcn_mfma_f32_16x16x32_bf16(Ahi, BL[j], acc[j], 0, 0, 0);
      acc[j] = __builtin_amdgcn_mfma_f32_16x16x32_bf16(Ahi, BH[j], acc[j], 0, 0, 0);
    }
    asm volatile("" ::: "memory");
    __builtin_amdgcn_s_barrier();
    asm volatile("" ::: "memory");
  }
#undef ISSUE
#undef AB
#undef BHB
#undef BLB

  // ---- epilogue: transpose scores to token-major LDS (aliases smem) ----
  float* Ls = (float*)smem;  // 64*68*4 = 17408 B <= 49152
#pragma unroll
  for (int j = 0; j < 4; ++j)
#pragma unroll
    for (int r = 0; r < 4; ++r)
      Ls[(16 * wave + 4 * lk + r) * LSTR + 16 * j + lr] = acc[j][r];
  __syncthreads();

  const float bv = bias[lane];
  for (int tt = 0; tt < 16; ++tt) {
    const int tl = wave * 16 + tt;
    const int t = row0 + tl;
    const float s = Ls[tl * LSTR + lane] + bv;

    float m = s;
#pragma unroll
    for (int off = 32; off >= 1; off >>= 1) m = fmaxf(m, __shfl_xor(m, off));
    const float e = expf(s - m);
    float sum = e;
#pragma unroll
    for (int off = 32; off >= 1; off >>= 1) sum += __shfl_xor(sum, off);
    const float p = e / sum;

    // top-9 on biased raw score, lowest-index tie-break (matches lax.top_k)
    float wsel = s;
    float rv = 0.f;
    int ri = 0;
    float prev = 0.f, mingap = 1e30f;
#pragma unroll
    for (int r = 0; r < 9; ++r) {
      float v = wsel;
      int ii = lane;
#pragma unroll
      for (int off = 32; off >= 1; off >>= 1) {
        const float ov = __shfl_xor(v, off);
        const int oi = __shfl_xor(ii, off);
        if (ov > v || (ov == v && oi < ii)) { v = ov; ii = oi; }
      }
      if (r > 0) mingap = fminf(mingap, prev - v);
      prev = v;
      const float pw = __shfl(p, ii);
      if (lane == r) { rv = pw; ri = ii; }
      if (lane == ii) wsel = -1e30f;
    }

    bool toC = false;
    if (mingap < TAU && cap > 0) {
      int pos = 0;
      if (lane == 0) pos = atomicAdd(cnt, 1);
      pos = __shfl(pos, 0);
      if (pos < cap) {
        if (lane == 0) list[pos] = t;
        toC = true;  // recompute kernel produces all outputs for this token
      }
    }
    if (!toC) {
      S[(size_t)t * NE + lane] = p;
      if (lane < K) {
        wout[(size_t)t * K + lane] = rv;
        iout[(size_t)t * K + lane] = (float)ri;
        atomicAdd(&hist_s[ri], 1);
      }
    }
  }
  __syncthreads();
  if (tid < NE) atomicAdd(&hist[tid], hist_s[tid]);
}

// -------- f64 finalize for one token (lanes 0..63) ---------------
__device__ __forceinline__ void finalize_token_f64(
    int t, int lane, double s, float* __restrict__ S, float* __restrict__ wout,
    float* __restrict__ iout, int* __restrict__ hist, int K) {
  double m = s;
#pragma unroll
  for (int off = 32; off >= 1; off >>= 1) m = fmax(m, __shfl_xor(m, off));
  const double ex = exp(s - m);
  double sum = ex;
#pragma unroll
  for (int off = 32; off >= 1; off >>= 1) sum += __shfl_xor(sum, off);
  const double p = ex / sum;
  S[(size_t)t * NE + lane] = (float)p;
  double wsel = s;
  double rv = 0.0;
  int ri = 0;
  for (int r = 0; r < K; ++r) {
    double v = wsel;
    int ii = lane;
#pragma unroll
    for (int off = 32; off >= 1; off >>= 1) {
      const double ov = __shfl_xor(v, off);
      const int oi = __shfl_xor(ii, off);
      if (ov > v || (ov == v && oi < ii)) { v = ov; ii = oi; }
    }
    const double pw = __shfl(p, ii);
    if (lane == r) { rv = pw; ri = ii; }
    if (lane == ii) wsel = -1e300;
  }
  if (lane < K) {
    wout[(size_t)t * K + lane] = (float)rv;
    iout[(size_t)t * K + lane] = (float)ri;
    atomicAdd(&hist[ri], 1);
  }
}

// ------- Kernel 2: f64 recompute, 1 token/block, grid 512 -------------------
__global__ __launch_bounds__(256) void recompute_f64(
    const float* __restrict__ X, const float* __restrict__ W,
    const float* __restrict__ bias, float* __restrict__ S,
    float* __restrict__ wout, float* __restrict__ iout,
    const int* __restrict__ cnt, const int* __restrict__ list,
    int* __restrict__ hist, int H, int K, int cap) {
  if (cap <= 0) return;
  __shared__ float4 xs[1024];  // one token row (16 KB)
  __shared__ double red[256];
  const int tid = threadIdx.x;
  const int n = min(*cnt, cap);
  const int H4 = H >> 2;
  for (int idx = blockIdx.x; idx < n; idx += gridDim.x) {
    const int t = list[idx];
    __syncthreads();  // xs reuse from previous iteration
    const float4* xg = reinterpret_cast<const float4*>(X + (size_t)t * H);
    for (int i = tid; i < H4; i += 256) xs[i] = xg[i];
    __syncthreads();
    const int e = tid & 63, sl = tid >> 6;
    const int seg = H4 >> 2;  // 256 float4 per slice
    const float4* wr =
        reinterpret_cast<const float4*>(W + (size_t)e * H) + (size_t)sl * seg;
    const float4* xr = &xs[sl * seg];
    double a0 = 0.0, a1 = 0.0;  // split accumulators (break f64 dep chain)
    for (int k = 0; k < seg; k += 2) {
      const float4 w0 = wr[k], w1 = wr[k + 1];
      const float4 v0 = xr[k], v1 = xr[k + 1];
      a0 = fma((double)v0.x, (double)w0.x, a0);
      a0 = fma((double)v0.y, (double)w0.y, a0);
      a0 = fma((double)v0.z, (double)w0.z, a0);
      a0 = fma((double)v0.w, (double)w0.w, a0);
      a1 = fma((double)v1.x, (double)w1.x, a1);
      a1 = fma((double)v1.y, (double)w1.y, a1);
      a1 = fma((double)v1.z, (double)w1.z, a1);
      a1 = fma((double)v1.w, (double)w1.w, a1);
    }
    red[tid] = a0 + a1;
    __syncthreads();
    if (tid < 64) {
      const double s =
          red[e] + red[64 + e] + red[128 + e] + red[192 + e] + (double)bias[e];
      finalize_token_f64(t, e, s, S, wout, iout, hist, K);
    }
  }
}

// ------------- Kernel 3: bias update from integer histogram -----------------
__global__ void bias_update(const int* __restrict__ hist,
                            const float* __restrict__ bias,
                            float* __restrict__ bout, float tpe) {
  const int e = threadIdx.x;
  const float d = (float)hist[e] - tpe;
  const float sg = (d > 0.f) ? 1.f : ((d < 0.f) ? -1.f : 0.f);
  bout[e] = bias[e] + 0.01f * sg;
}

extern "C" void kernel_launch(void* const* d_in, const int* in_sizes, int n_in,
                              void* d_out, int out_size, void* d_ws, size_t ws_size,
                              hipStream_t stream) {
  const float* x = (const float*)d_in[0];
  const float* w = (const float*)d_in[1];
  const float* bias = (const float*)d_in[2];
  const int E = in_sizes[2];                       // 64
  const int H = in_sizes[1] / E;                   // 4096
  const long long N = (long long)in_sizes[0] / H;  // 32768 tokens
  const int K = (int)(((long long)out_size - N * E - E) / (2 * N));  // 8

  float* S = (float*)d_out;            // [N][E] probs
  float* wout = S + (size_t)N * E;     // [N][K]
  float* iout = wout + (size_t)N * K;  // [N][K] indices as float
  float* bout = iout + (size_t)N * K;  // [E]

  // ws: [0,4) cnt | [256,512) hist | Whi_f @4KB (512KB) | Wlo_f | list after
  int* cnt = (int*)d_ws;
  int* hist = (int*)d_ws + 64;
  const size_t whalf = (size_t)E * H * sizeof(__bf16);  // 512 KB
  __bf16* Whi = (__bf16*)((char*)d_ws + 4096);
  __bf16* Wlo = (__bf16*)((char*)d_ws + 4096 + whalf);
  const size_t listoff = 4096 + 2 * whalf;
  int* list = (int*)((char*)d_ws + listoff);
  int cap = 0;
  if (ws_size > listoff + 65536)
    cap = (int)min((size_t)32768, (ws_size - listoff) / 4);

  zero512<<<dim3(1), dim3(128), 0, stream>>>((int*)d_ws);
  const int n8 = E * H / 8;
  wconvert<<<dim3((n8 + 255) / 256), 256, 0, stream>>>(w, Whi, Wlo, n8, H);
  gemm_fused<<<dim3((int)(N / 64)), 256, 0, stream>>>(
      x, Whi, Wlo, bias, S, wout, iout, cnt, hist, list, cap, H, K);
  recompute_f64<<<dim3(512), 256, 0, stream>>>(x, w, bias, S, wout, iout, cnt,
                                               list, hist, H, K, cap);
  bias_update<<<dim3(1), dim3(E), 0, stream>>>(hist, bias, bout,
                                               (float)((double)N * K / E));
}

// Round 9
// 345.315 us; speedup vs baseline: 2.9013x; 1.0620x over previous
//
#include <hip/hip_runtime.h>

#define NE 64
#define TAU 2.5e-4f
#define LSTR 68  // 68 mod 32 = 4 -> 2-way (free) LDS access in epilogue

typedef __bf16 bf16x8 __attribute__((ext_vector_type(8)));
typedef float f32x4 __attribute__((ext_vector_type(4)));

// split f32 -> bf16 hi + bf16 lo (hi RNE, lo = RNE(x - hi); x-hi exact in f32)
__device__ __forceinline__ void split8(const float4 a0, const float4 a1,
                                       bf16x8& hi, bf16x8& lo) {
  const float xs[8] = {a0.x, a0.y, a0.z, a0.w, a1.x, a1.y, a1.z, a1.w};
#pragma unroll
  for (int i = 0; i < 8; ++i) {
    const __bf16 h = (__bf16)xs[i];
    hi[i] = h;
    lo[i] = (__bf16)(xs[i] - (float)h);
  }
}

// async global->LDS, 16B/lane; LDS dest = wave-uniform base + lane*16
__device__ __forceinline__ void gld16(const void* g, void* l) {
  __builtin_amdgcn_global_load_lds(
      (const __attribute__((address_space(1))) void*)g,
      (__attribute__((address_space(3))) void*)l, 16, 0, 0);
}

// ---- Kernel Z: zero cnt+hist ------------------------------------------------
__global__ void zero512(int* __restrict__ p) { p[threadIdx.x] = 0; }

// ---- Kernel 0: W -> bf16 hi/lo in FRAGMENT-MAJOR 32-k tiles (1 MB, once) ---
// elem(tt, j, lk, lr, kr) = tt*2048 + j*512 + (lk*16+lr)*8 + kr
// where W-row e = 16j+lr, k = 32tt + 8lk + kr.
__global__ __launch_bounds__(256) void wconvert(const float* __restrict__ W,
                                                __bf16* __restrict__ Whi,
                                                __bf16* __restrict__ Wlo,
                                                int n8, int H) {
  const int i = blockIdx.x * 256 + threadIdx.x;
  if (i >= n8) return;
  const int hc = H >> 3;
  const int e = i / hc;
  const int k0 = (i - e * hc) * 8;
  const float4 a0 = *reinterpret_cast<const float4*>(W + (size_t)e * H + k0);
  const float4 a1 =
      *reinterpret_cast<const float4*>(W + (size_t)e * H + k0 + 4);
  bf16x8 hi, lo;
  split8(a0, a1, hi, lo);
  const int tt = k0 >> 5, lk = (k0 >> 3) & 3, j = e >> 4, lr = e & 15;
  const size_t off = (size_t)tt * 2048 + j * 512 + (lk * 16 + lr) * 8;
  *reinterpret_cast<bf16x8*>(Whi + off) = hi;
  *reinterpret_cast<bf16x8*>(Wlo + off) = lo;
}

// ------- Kernel 1: split-bf16 MFMA GEMM, BK=64, double-buffered gload_lds ---
// Block = 4 waves, 64 tokens. Per 64-k step per wave: 8 gld16 (4 A + 2 Bh +
// 2 Bl), counted vmcnt(8), 2 raw s_barriers, 24 MFMA + 20 ds_read_b128.
// A LDS [16 rows][16 slots of 16B] per wave, slot XOR-swizzled (slot^(row&7))
// via pre-swizzled GLOBAL source (LDS dest linear). B fragment-major,
// lane-contiguous. MFMA/C layout identical to rounds 5-8 (HW-validated).
__global__ __launch_bounds__(256, 2) void gemm_fused(
    const float* __restrict__ X, const __bf16* __restrict__ Whi,
    const __bf16* __restrict__ Wlo, const float* __restrict__ bias,
    float* __restrict__ S, float* __restrict__ wout, float* __restrict__ iout,
    int* __restrict__ cnt, int* __restrict__ hist, int* __restrict__ list,
    int cap, int H, int K) {
  __shared__ alignas(16) char smem[65536];
  __shared__ int hist_s[NE];
  const int tid = threadIdx.x;
  const int lane = tid & 63;
  const int wave = tid >> 6;
  if (tid < NE) hist_s[tid] = 0;
  const int lr = lane & 15;  // fragment row/col
  const int lk = lane >> 4;  // k sub-chunk
  const int row0 = blockIdx.x * 64;

  // A staging sources: instr p (0..3), lane -> row rr = 4p + (lane>>4),
  // phys slot sp = lane&15 holds logical chunk sp ^ (rr&7).
  const float* srcA[4];
#pragma unroll
  for (int p = 0; p < 4; ++p) {
    const int rr = 4 * p + (lane >> 4);
    const int sp = lane & 15;
    srcA[p] = X + (size_t)(row0 + 16 * wave + rr) * H + 4 * (sp ^ (rr & 7));
  }
  const __bf16* srcBh = Whi + wave * 512 + lane * 8;
  const __bf16* srcBl = Wlo + wave * 512 + lane * 8;

#define AF(buf) ((float*)smem + (size_t)(buf)*4096)
#define BHF(buf) ((__bf16*)(smem + 32768) + (size_t)(buf)*4096)
#define BLF(buf) ((__bf16*)(smem + 49152) + (size_t)(buf)*4096)
#define ISSUE(t, buf)                                                   \
  do {                                                                  \
    _Pragma("unroll") for (int p = 0; p < 4; ++p)                       \
        gld16(srcA[p] + 64 * (size_t)(t),                               \
              AF(buf) + wave * 1024 + p * 256);                         \
    gld16(srcBh + 4096 * (size_t)(t), BHF(buf) + wave * 512);           \
    gld16(srcBh + 4096 * (size_t)(t) + 2048,                            \
          BHF(buf) + 2048 + wave * 512);                                \
    gld16(srcBl + 4096 * (size_t)(t), BLF(buf) + wave * 512);           \
    gld16(srcBl + 4096 * (size_t)(t) + 2048,                            \
          BLF(buf) + 2048 + wave * 512);                                \
  } while (0)

  f32x4 acc[4] = {};
  const int T2 = H / 64;  // 64 iterations
  const int swz = lr & 7;

  ISSUE(0, 0);
  for (int t = 0; t < T2; ++t) {
    const int buf = t & 1;
    if (t + 1 < T2) {
      ISSUE(t + 1, buf ^ 1);
      asm volatile("s_waitcnt vmcnt(8)" ::: "memory");  // tile t landed
    } else {
      asm volatile("s_waitcnt vmcnt(0)" ::: "memory");
    }
    __builtin_amdgcn_s_barrier();
    asm volatile("" ::: "memory");

    const float* Aw = AF(buf) + wave * 1024 + lr * 64;  // my row base
#pragma unroll
    for (int kk = 0; kk < 2; ++kk) {
      const int c = 8 * kk + 2 * lk;  // even logical chunk
      const float4 f0 =
          *reinterpret_cast<const float4*>(Aw + 4 * (c ^ swz));
      const float4 f1 =
          *reinterpret_cast<const float4*>(Aw + 4 * ((c + 1) ^ swz));
      bf16x8 Ahi, Alo;
      split8(f0, f1, Ahi, Alo);
      const __bf16* Bh = BHF(buf) + kk * 2048;
      const __bf16* Bl = BLF(buf) + kk * 2048;
#pragma unroll
      for (int j = 0; j < 4; ++j) {
        const bf16x8 BH =
            *reinterpret_cast<const bf16x8*>(Bh + j * 512 + lane * 8);
        const bf16x8 BL =
            *reinterpret_cast<const bf16x8*>(Bl + j * 512 + lane * 8);
        acc[j] =
            __builtin_amdgcn_mfma_f32_16x16x32_bf16(Alo, BH, acc[j], 0, 0, 0);
        acc[j] =
            __builtin_amdgcn_mfma_f32_16x16x32_bf16(Ahi, BL, acc[j], 0, 0, 0);
        acc[j] =
            __builtin_amdgcn_mfma_f32_16x16x32_bf16(Ahi, BH, acc[j], 0, 0, 0);
      }
    }
    asm volatile("" ::: "memory");
    __builtin_amdgcn_s_barrier();
    asm volatile("" ::: "memory");
  }
#undef ISSUE
#undef AF
#undef BHF
#undef BLF

  // ---- epilogue: transpose scores to token-major LDS (aliases smem) ----
  float* Ls = (float*)smem;  // 64*68*4 = 17408 B <= 65536
#pragma unroll
  for (int j = 0; j < 4; ++j)
#pragma unroll
    for (int r = 0; r < 4; ++r)
      Ls[(16 * wave + 4 * lk + r) * LSTR + 16 * j + lr] = acc[j][r];
  __syncthreads();

  const float bv = bias[lane];
  for (int tt = 0; tt < 16; ++tt) {
    const int tl = wave * 16 + tt;
    const int t = row0 + tl;
    const float s = Ls[tl * LSTR + lane] + bv;

    float m = s;
#pragma unroll
    for (int off = 32; off >= 1; off >>= 1) m = fmaxf(m, __shfl_xor(m, off));
    const float e = expf(s - m);
    float sum = e;
#pragma unroll
    for (int off = 32; off >= 1; off >>= 1) sum += __shfl_xor(sum, off);
    const float p = e / sum;

    // top-9 on biased raw score, lowest-index tie-break (matches lax.top_k)
    float wsel = s;
    float rv = 0.f;
    int ri = 0;
    float prev = 0.f, mingap = 1e30f;
#pragma unroll
    for (int r = 0; r < 9; ++r) {
      float v = wsel;
      int ii = lane;
#pragma unroll
      for (int off = 32; off >= 1; off >>= 1) {
        const float ov = __shfl_xor(v, off);
        const int oi = __shfl_xor(ii, off);
        if (ov > v || (ov == v && oi < ii)) { v = ov; ii = oi; }
      }
      if (r > 0) mingap = fminf(mingap, prev - v);
      prev = v;
      const float pw = __shfl(p, ii);
      if (lane == r) { rv = pw; ri = ii; }
      if (lane == ii) wsel = -1e30f;
    }

    bool toC = false;
    if (mingap < TAU && cap > 0) {
      int pos = 0;
      if (lane == 0) pos = atomicAdd(cnt, 1);
      pos = __shfl(pos, 0);
      if (pos < cap) {
        if (lane == 0) list[pos] = t;
        toC = true;  // recompute kernel produces all outputs for this token
      }
    }
    if (!toC) {
      S[(size_t)t * NE + lane] = p;
      if (lane < K) {
        wout[(size_t)t * K + lane] = rv;
        iout[(size_t)t * K + lane] = (float)ri;
        atomicAdd(&hist_s[ri], 1);
      }
    }
  }
  __syncthreads();
  if (tid < NE) atomicAdd(&hist[tid], hist_s[tid]);
}

// -------- f64 finalize for one token (lanes 0..63) ---------------
__device__ __forceinline__ void finalize_token_f64(
    int t, int lane, double s, float* __restrict__ S, float* __restrict__ wout,
    float* __restrict__ iout, int* __restrict__ hist, int K) {
  double m = s;
#pragma unroll
  for (int off = 32; off >= 1; off >>= 1) m = fmax(m, __shfl_xor(m, off));
  const double ex = exp(s - m);
  double sum = ex;
#pragma unroll
  for (int off = 32; off >= 1; off >>= 1) sum += __shfl_xor(sum, off);
  const double p = ex / sum;
  S[(size_t)t * NE + lane] = (float)p;
  double wsel = s;
  double rv = 0.0;
  int ri = 0;
  for (int r = 0; r < K; ++r) {
    double v = wsel;
    int ii = lane;
#pragma unroll
    for (int off = 32; off >= 1; off >>= 1) {
      const double ov = __shfl_xor(v, off);
      const int oi = __shfl_xor(ii, off);
      if (ov > v || (ov == v && oi < ii)) { v = ov; ii = oi; }
    }
    const double pw = __shfl(p, ii);
    if (lane == r) { rv = pw; ri = ii; }
    if (lane == ii) wsel = -1e300;
  }
  if (lane < K) {
    wout[(size_t)t * K + lane] = (float)rv;
    iout[(size_t)t * K + lane] = (float)ri;
    atomicAdd(&hist[ri], 1);
  }
}

// ------- Kernel 2: f64 recompute, 1 token/block, grid 512 -------------------
__global__ __launch_bounds__(256) void recompute_f64(
    const float* __restrict__ X, const float* __restrict__ W,
    const float* __restrict__ bias, float* __restrict__ S,
    float* __restrict__ wout, float* __restrict__ iout,
    const int* __restrict__ cnt, const int* __restrict__ list,
    int* __restrict__ hist, int H, int K, int cap) {
  if (cap <= 0) return;
  __shared__ float4 xs[1024];  // one token row (16 KB)
  __shared__ double red[256];
  const int tid = threadIdx.x;
  const int n = min(*cnt, cap);
  const int H4 = H >> 2;
  for (int idx = blockIdx.x; idx < n; idx += gridDim.x) {
    const int t = list[idx];
    __syncthreads();  // xs reuse from previous iteration
    const float4* xg = reinterpret_cast<const float4*>(X + (size_t)t * H);
    for (int i = tid; i < H4; i += 256) xs[i] = xg[i];
    __syncthreads();
    const int e = tid & 63, sl = tid >> 6;
    const int seg = H4 >> 2;  // 256 float4 per slice
    const float4* wr =
        reinterpret_cast<const float4*>(W + (size_t)e * H) + (size_t)sl * seg;
    const float4* xr = &xs[sl * seg];
    double a0 = 0.0, a1 = 0.0;  // split accumulators (break f64 dep chain)
    for (int k = 0; k < seg; k += 2) {
      const float4 w0 = wr[k], w1 = wr[k + 1];
      const float4 v0 = xr[k], v1 = xr[k + 1];
      a0 = fma((double)v0.x, (double)w0.x, a0);
      a0 = fma((double)v0.y, (double)w0.y, a0);
      a0 = fma((double)v0.z, (double)w0.z, a0);
      a0 = fma((double)v0.w, (double)w0.w, a0);
      a1 = fma((double)v1.x, (double)w1.x, a1);
      a1 = fma((double)v1.y, (double)w1.y, a1);
      a1 = fma((double)v1.z, (double)w1.z, a1);
      a1 = fma((double)v1.w, (double)w1.w, a1);
    }
    red[tid] = a0 + a1;
    __syncthreads();
    if (tid < 64) {
      const double s =
          red[e] + red[64 + e] + red[128 + e] + red[192 + e] + (double)bias[e];
      finalize_token_f64(t, e, s, S, wout, iout, hist, K);
    }
  }
}

// ------------- Kernel 3: bias update from integer histogram -----------------
__global__ void bias_update(const int* __restrict__ hist,
                            const float* __restrict__ bias,
                            float* __restrict__ bout, float tpe) {
  const int e = threadIdx.x;
  const float d = (float)hist[e] - tpe;
  const float sg = (d > 0.f) ? 1.f : ((d < 0.f) ? -1.f : 0.f);
  bout[e] = bias[e] + 0.01f * sg;
}

extern "C" void kernel_launch(void* const* d_in, const int* in_sizes, int n_in,
                              void* d_out, int out_size, void* d_ws, size_t ws_size,
                              hipStream_t stream) {
  const float* x = (const float*)d_in[0];
  const float* w = (const float*)d_in[1];
  const float* bias = (const float*)d_in[2];
  const int E = in_sizes[2];                       // 64
  const int H = in_sizes[1] / E;                   // 4096
  const long long N = (long long)in_sizes[0] / H;  // 32768 tokens
  const int K = (int)(((long long)out_size - N * E - E) / (2 * N));  // 8

  float* S = (float*)d_out;            // [N][E] probs
  float* wout = S + (size_t)N * E;     // [N][K]
  float* iout = wout + (size_t)N * K;  // [N][K] indices as float
  float* bout = iout + (size_t)N * K;  // [E]

  // ws: [0,4) cnt | [256,512) hist | Whi_f @4KB (512KB) | Wlo_f | list after
  int* cnt = (int*)d_ws;
  int* hist = (int*)d_ws + 64;
  const size_t whalf = (size_t)E * H * sizeof(__bf16);  // 512 KB
  __bf16* Whi = (__bf16*)((char*)d_ws + 4096);
  __bf16* Wlo = (__bf16*)((char*)d_ws + 4096 + whalf);
  const size_t listoff = 4096 + 2 * whalf;
  int* list = (int*)((char*)d_ws + listoff);
  int cap = 0;
  if (ws_size > listoff + 65536)
    cap = (int)min((size_t)32768, (ws_size - listoff) / 4);

  zero512<<<dim3(1), dim3(128), 0, stream>>>((int*)d_ws);
  const int n8 = E * H / 8;
  wconvert<<<dim3((n8 + 255) / 256), 256, 0, stream>>>(w, Whi, Wlo, n8, H);
  gemm_fused<<<dim3((int)(N / 64)), 256, 0, stream>>>(
      x, Whi, Wlo, bias, S, wout, iout, cnt, hist, list, cap, H, K);
  recompute_f64<<<dim3(512), 256, 0, stream>>>(x, w, bias, S, wout, iout, cnt,
                                               list, hist, H, K, cap);
  bias_update<<<dim3(1), dim3(E), 0, stream>>>(hist, bias, bout,
                                               (float)((double)N * K / E));
}

// Round 10
// 284.799 us; speedup vs baseline: 3.5178x; 1.2125x over previous
//
#include <hip/hip_runtime.h>

#define NE 64
#define TAU 1e-4f  // 4-term split-bf16 score sigma ~5e-6 -> 20-sigma guard
#define LSTR 68    // 68 mod 32 = 4 -> 2-way (free) LDS access in epilogue

typedef __bf16 bf16x8 __attribute__((ext_vector_type(8)));
typedef float f32x4 __attribute__((ext_vector_type(4)));

// split f32 -> bf16 hi + bf16 lo (hi RNE, lo = RNE(x - hi); x-hi exact in f32)
__device__ __forceinline__ void split8(const float4 a0, const float4 a1,
                                       bf16x8& hi, bf16x8& lo) {
  const float xs[8] = {a0.x, a0.y, a0.z, a0.w, a1.x, a1.y, a1.z, a1.w};
#pragma unroll
  for (int i = 0; i < 8; ++i) {
    const __bf16 h = (__bf16)xs[i];
    hi[i] = h;
    lo[i] = (__bf16)(xs[i] - (float)h);
  }
}

// async global->LDS, 16B/lane; LDS dest = wave-uniform base + lane*16
__device__ __forceinline__ void gld16(const void* g, void* l) {
  __builtin_amdgcn_global_load_lds(
      (const __attribute__((address_space(1))) void*)g,
      (__attribute__((address_space(3))) void*)l, 16, 0, 0);
}

// ---- Kernel Z: zero cnt+hist ------------------------------------------------
__global__ void zero512(int* __restrict__ p) { p[threadIdx.x] = 0; }

// ---- Kernel 0: W -> bf16 hi/lo in FRAGMENT-MAJOR 32-k tiles (1 MB, once) ---
// elem(tt, j, lk, lr, kr) = tt*2048 + j*512 + (lk*16+lr)*8 + kr
// where W-row e = 16j+lr, k = 32tt + 8lk + kr.
__global__ __launch_bounds__(256) void wconvert(const float* __restrict__ W,
                                                __bf16* __restrict__ Whi,
                                                __bf16* __restrict__ Wlo,
                                                int n8, int H) {
  const int i = blockIdx.x * 256 + threadIdx.x;
  if (i >= n8) return;
  const int hc = H >> 3;
  const int e = i / hc;
  const int k0 = (i - e * hc) * 8;
  const float4 a0 = *reinterpret_cast<const float4*>(W + (size_t)e * H + k0);
  const float4 a1 =
      *reinterpret_cast<const float4*>(W + (size_t)e * H + k0 + 4);
  bf16x8 hi, lo;
  split8(a0, a1, hi, lo);
  const int tt = k0 >> 5, lk = (k0 >> 3) & 3, j = e >> 4, lr = e & 15;
  const size_t off = (size_t)tt * 2048 + j * 512 + (lk * 16 + lr) * 8;
  *reinterpret_cast<bf16x8*>(Whi + off) = hi;
  *reinterpret_cast<bf16x8*>(Wlo + off) = lo;
}

// ------- Kernel 1: 4-term split-bf16 MFMA GEMM, BK=64, double-buffered ------
// Block = 4 waves, 64 tokens. Per 64-k step per wave: 8 gld16, counted
// vmcnt(8), 2 raw s_barriers, 32 MFMA (hi*hi + hi*lo + lo*hi + lo*lo: full
// f32-accuracy product) + 20 ds_read_b128. A LDS slot-swizzled via
// pre-swizzled GLOBAL source (LDS dest linear). B fragment-major.
__global__ __launch_bounds__(256, 2) void gemm_fused(
    const float* __restrict__ X, const __bf16* __restrict__ Whi,
    const __bf16* __restrict__ Wlo, const float* __restrict__ bias,
    float* __restrict__ S, float* __restrict__ wout, float* __restrict__ iout,
    int* __restrict__ cnt, int* __restrict__ hist, int* __restrict__ list,
    int cap, int H, int K) {
  __shared__ alignas(16) char smem[65536];
  __shared__ int hist_s[NE];
  const int tid = threadIdx.x;
  const int lane = tid & 63;
  const int wave = tid >> 6;
  if (tid < NE) hist_s[tid] = 0;
  const int lr = lane & 15;  // fragment row/col
  const int lk = lane >> 4;  // k sub-chunk
  const int row0 = blockIdx.x * 64;

  // A staging sources: instr p (0..3), lane -> row rr = 4p + (lane>>4),
  // phys slot sp = lane&15 holds logical chunk sp ^ (rr&7).
  const float* srcA[4];
#pragma unroll
  for (int p = 0; p < 4; ++p) {
    const int rr = 4 * p + (lane >> 4);
    const int sp = lane & 15;
    srcA[p] = X + (size_t)(row0 + 16 * wave + rr) * H + 4 * (sp ^ (rr & 7));
  }
  const __bf16* srcBh = Whi + wave * 512 + lane * 8;
  const __bf16* srcBl = Wlo + wave * 512 + lane * 8;

#define AF(buf) ((float*)smem + (size_t)(buf)*4096)
#define BHF(buf) ((__bf16*)(smem + 32768) + (size_t)(buf)*4096)
#define BLF(buf) ((__bf16*)(smem + 49152) + (size_t)(buf)*4096)
#define ISSUE(t, buf)                                                   \
  do {                                                                  \
    _Pragma("unroll") for (int p = 0; p < 4; ++p)                       \
        gld16(srcA[p] + 64 * (size_t)(t),                               \
              AF(buf) + wave * 1024 + p * 256);                         \
    gld16(srcBh + 4096 * (size_t)(t), BHF(buf) + wave * 512);           \
    gld16(srcBh + 4096 * (size_t)(t) + 2048,                            \
          BHF(buf) + 2048 + wave * 512);                                \
    gld16(srcBl + 4096 * (size_t)(t), BLF(buf) + wave * 512);           \
    gld16(srcBl + 4096 * (size_t)(t) + 2048,                            \
          BLF(buf) + 2048 + wave * 512);                                \
  } while (0)

  f32x4 acc[4] = {};
  const int T2 = H / 64;  // 64 iterations
  const int swz = lr & 7;

  ISSUE(0, 0);
  for (int t = 0; t < T2; ++t) {
    const int buf = t & 1;
    if (t + 1 < T2) {
      ISSUE(t + 1, buf ^ 1);
      asm volatile("s_waitcnt vmcnt(8)" ::: "memory");  // tile t landed
    } else {
      asm volatile("s_waitcnt vmcnt(0)" ::: "memory");
    }
    __builtin_amdgcn_s_barrier();
    asm volatile("" ::: "memory");

    const float* Aw = AF(buf) + wave * 1024 + lr * 64;  // my row base
#pragma unroll
    for (int kk = 0; kk < 2; ++kk) {
      const int c = 8 * kk + 2 * lk;  // even logical chunk
      const float4 f0 =
          *reinterpret_cast<const float4*>(Aw + 4 * (c ^ swz));
      const float4 f1 =
          *reinterpret_cast<const float4*>(Aw + 4 * ((c + 1) ^ swz));
      bf16x8 Ahi, Alo;
      split8(f0, f1, Ahi, Alo);
      const __bf16* Bh = BHF(buf) + kk * 2048;
      const __bf16* Bl = BLF(buf) + kk * 2048;
#pragma unroll
      for (int j = 0; j < 4; ++j) {
        const bf16x8 BH =
            *reinterpret_cast<const bf16x8*>(Bh + j * 512 + lane * 8);
        const bf16x8 BL =
            *reinterpret_cast<const bf16x8*>(Bl + j * 512 + lane * 8);
        acc[j] =
            __builtin_amdgcn_mfma_f32_16x16x32_bf16(Alo, BL, acc[j], 0, 0, 0);
        acc[j] =
            __builtin_amdgcn_mfma_f32_16x16x32_bf16(Alo, BH, acc[j], 0, 0, 0);
        acc[j] =
            __builtin_amdgcn_mfma_f32_16x16x32_bf16(Ahi, BL, acc[j], 0, 0, 0);
        acc[j] =
            __builtin_amdgcn_mfma_f32_16x16x32_bf16(Ahi, BH, acc[j], 0, 0, 0);
      }
    }
    asm volatile("" ::: "memory");
    __builtin_amdgcn_s_barrier();
    asm volatile("" ::: "memory");
  }
#undef ISSUE
#undef AF
#undef BHF
#undef BLF

  // ---- epilogue: transpose scores to token-major LDS (aliases smem) ----
  float* Ls = (float*)smem;  // 64*68*4 = 17408 B <= 65536
#pragma unroll
  for (int j = 0; j < 4; ++j)
#pragma unroll
    for (int r = 0; r < 4; ++r)
      Ls[(16 * wave + 4 * lk + r) * LSTR + 16 * j + lr] = acc[j][r];
  __syncthreads();

  const float bv = bias[lane];
  for (int tt = 0; tt < 16; ++tt) {
    const int tl = wave * 16 + tt;
    const int t = row0 + tl;
    const float s = Ls[tl * LSTR + lane] + bv;

    float m = s;
#pragma unroll
    for (int off = 32; off >= 1; off >>= 1) m = fmaxf(m, __shfl_xor(m, off));
    const float e = expf(s - m);
    float sum = e;
#pragma unroll
    for (int off = 32; off >= 1; off >>= 1) sum += __shfl_xor(sum, off);
    const float p = e / sum;

    // top-9 on biased raw score, lowest-index tie-break (matches lax.top_k)
    float wsel = s;
    float rv = 0.f;
    int ri = 0;
    float prev = 0.f, mingap = 1e30f;
#pragma unroll
    for (int r = 0; r < 9; ++r) {
      float v = wsel;
      int ii = lane;
#pragma unroll
      for (int off = 32; off >= 1; off >>= 1) {
        const float ov = __shfl_xor(v, off);
        const int oi = __shfl_xor(ii, off);
        if (ov > v || (ov == v && oi < ii)) { v = ov; ii = oi; }
      }
      if (r > 0) mingap = fminf(mingap, prev - v);
      prev = v;
      const float pw = __shfl(p, ii);
      if (lane == r) { rv = pw; ri = ii; }
      if (lane == ii) wsel = -1e30f;
    }

    bool toC = false;
    if (mingap < TAU && cap > 0) {
      int pos = 0;
      if (lane == 0) pos = atomicAdd(cnt, 1);
      pos = __shfl(pos, 0);
      if (pos < cap) {
        if (lane == 0) list[pos] = t;
        toC = true;  // recompute kernel produces all outputs for this token
      }
    }
    if (!toC) {
      S[(size_t)t * NE + lane] = p;
      if (lane < K) {
        wout[(size_t)t * K + lane] = rv;
        iout[(size_t)t * K + lane] = (float)ri;
        atomicAdd(&hist_s[ri], 1);
      }
    }
  }
  __syncthreads();
  if (tid < NE) atomicAdd(&hist[tid], hist_s[tid]);
}

// -------- f64 finalize for one token (lanes 0..63) ---------------
__device__ __forceinline__ void finalize_token_f64(
    int t, int lane, double s, float* __restrict__ S, float* __restrict__ wout,
    float* __restrict__ iout, int* __restrict__ hist, int K) {
  double m = s;
#pragma unroll
  for (int off = 32; off >= 1; off >>= 1) m = fmax(m, __shfl_xor(m, off));
  const double ex = exp(s - m);
  double sum = ex;
#pragma unroll
  for (int off = 32; off >= 1; off >>= 1) sum += __shfl_xor(sum, off);
  const double p = ex / sum;
  S[(size_t)t * NE + lane] = (float)p;
  double wsel = s;
  double rv = 0.0;
  int ri = 0;
  for (int r = 0; r < K; ++r) {
    double v = wsel;
    int ii = lane;
#pragma unroll
    for (int off = 32; off >= 1; off >>= 1) {
      const double ov = __shfl_xor(v, off);
      const int oi = __shfl_xor(ii, off);
      if (ov > v || (ov == v && oi < ii)) { v = ov; ii = oi; }
    }
    const double pw = __shfl(p, ii);
    if (lane == r) { rv = pw; ri = ii; }
    if (lane == ii) wsel = -1e300;
  }
  if (lane < K) {
    wout[(size_t)t * K + lane] = (float)rv;
    iout[(size_t)t * K + lane] = (float)ri;
    atomicAdd(&hist[ri], 1);
  }
}

// ------- Kernel 2: f64 recompute, 1 token/block, grid 512 -------------------
__global__ __launch_bounds__(256) void recompute_f64(
    const float* __restrict__ X, const float* __restrict__ W,
    const float* __restrict__ bias, float* __restrict__ S,
    float* __restrict__ wout, float* __restrict__ iout,
    const int* __restrict__ cnt, const int* __restrict__ list,
    int* __restrict__ hist, int H, int K, int cap) {
  if (cap <= 0) return;
  __shared__ float4 xs[1024];  // one token row (16 KB)
  __shared__ double red[256];
  const int tid = threadIdx.x;
  const int n = min(*cnt, cap);
  const int H4 = H >> 2;
  for (int idx = blockIdx.x; idx < n; idx += gridDim.x) {
    const int t = list[idx];
    __syncthreads();  // xs reuse from previous iteration
    const float4* xg = reinterpret_cast<const float4*>(X + (size_t)t * H);
    for (int i = tid; i < H4; i += 256) xs[i] = xg[i];
    __syncthreads();
    const int e = tid & 63, sl = tid >> 6;
    const int seg = H4 >> 2;  // 256 float4 per slice
    const float4* wr =
        reinterpret_cast<const float4*>(W + (size_t)e * H) + (size_t)sl * seg;
    const float4* xr = &xs[sl * seg];
    double a0 = 0.0, a1 = 0.0;  // split accumulators (break f64 dep chain)
    for (int k = 0; k < seg; k += 2) {
      const float4 w0 = wr[k], w1 = wr[k + 1];
      const float4 v0 = xr[k], v1 = xr[k + 1];
      a0 = fma((double)v0.x, (double)w0.x, a0);
      a0 = fma((double)v0.y, (double)w0.y, a0);
      a0 = fma((double)v0.z, (double)w0.z, a0);
      a0 = fma((double)v0.w, (double)w0.w, a0);
      a1 = fma((double)v1.x, (double)w1.x, a1);
      a1 = fma((double)v1.y, (double)w1.y, a1);
      a1 = fma((double)v1.z, (double)w1.z, a1);
      a1 = fma((double)v1.w, (double)w1.w, a1);
    }
    red[tid] = a0 + a1;
    __syncthreads();
    if (tid < 64) {
      const double s =
          red[e] + red[64 + e] + red[128 + e] + red[192 + e] + (double)bias[e];
      finalize_token_f64(t, e, s, S, wout, iout, hist, K);
    }
  }
}

// ------------- Kernel 3: bias update from integer histogram -----------------
__global__ void bias_update(const int* __restrict__ hist,
                            const float* __restrict__ bias,
                            float* __restrict__ bout, float tpe) {
  const int e = threadIdx.x;
  const float d = (float)hist[e] - tpe;
  const float sg = (d > 0.f) ? 1.f : ((d < 0.f) ? -1.f : 0.f);
  bout[e] = bias[e] + 0.01f * sg;
}

extern "C" void kernel_launch(void* const* d_in, const int* in_sizes, int n_in,
                              void* d_out, int out_size, void* d_ws, size_t ws_size,
                              hipStream_t stream) {
  const float* x = (const float*)d_in[0];
  const float* w = (const float*)d_in[1];
  const float* bias = (const float*)d_in[2];
  const int E = in_sizes[2];                       // 64
  const int H = in_sizes[1] / E;                   // 4096
  const long long N = (long long)in_sizes[0] / H;  // 32768 tokens
  const int K = (int)(((long long)out_size - N * E - E) / (2 * N));  // 8

  float* S = (float*)d_out;            // [N][E] probs
  float* wout = S + (size_t)N * E;     // [N][K]
  float* iout = wout + (size_t)N * K;  // [N][K] indices as float
  float* bout = iout + (size_t)N * K;  // [E]

  // ws: [0,4) cnt | [256,512) hist | Whi_f @4KB (512KB) | Wlo_f | list after
  int* cnt = (int*)d_ws;
  int* hist = (int*)d_ws + 64;
  const size_t whalf = (size_t)E * H * sizeof(__bf16);  // 512 KB
  __bf16* Whi = (__bf16*)((char*)d_ws + 4096);
  __bf16* Wlo = (__bf16*)((char*)d_ws + 4096 + whalf);
  const size_t listoff = 4096 + 2 * whalf;
  int* list = (int*)((char*)d_ws + listoff);
  int cap = 0;
  if (ws_size > listoff + 65536)
    cap = (int)min((size_t)32768, (ws_size - listoff) / 4);

  zero512<<<dim3(1), dim3(128), 0, stream>>>((int*)d_ws);
  const int n8 = E * H / 8;
  wconvert<<<dim3((n8 + 255) / 256), 256, 0, stream>>>(w, Whi, Wlo, n8, H);
  gemm_fused<<<dim3((int)(N / 64)), 256, 0, stream>>>(
      x, Whi, Wlo, bias, S, wout, iout, cnt, hist, list, cap, H, K);
  recompute_f64<<<dim3(512), 256, 0, stream>>>(x, w, bias, S, wout, iout, cnt,
                                               list, hist, H, K, cap);
  bias_update<<<dim3(1), dim3(E), 0, stream>>>(hist, bias, bout,
                                               (float)((double)N * K / E));
}